// Round 2
// 385.620 us; speedup vs baseline: 1.0036x; 1.0036x over previous
//
#include <hip/hip_runtime.h>
#include <hip/hip_bf16.h>

#define NN 8192
#define EE 262144
#define BB 8
#define LL 1024
#define HH 8
#define DD 256
#define DFFN 2048

typedef short s8v __attribute__((ext_vector_type(8)));
typedef float f32x4 __attribute__((ext_vector_type(4)));
typedef unsigned short ushort;

__device__ inline ushort f2bf(float f) {
    unsigned u = __float_as_uint(f);
    u = (u + 0x7fffu + ((u >> 16) & 1u)) >> 16;
    return (ushort)u;
}
__device__ inline float bf2f(ushort u) {
    return __uint_as_float(((unsigned)u) << 16);
}

// ---------------------------------------------------------------------------
// ff1 GEMM: 128x256 tile, BK=64, mod-8 XOR-swizzled LDS, bias+relu+bf16 out.
// acc[4][8] per wave (64 MFMA per K-step per wave). Grid (M/128, N/256).
// ---------------------------------------------------------------------------
__global__ __launch_bounds__(256, 2) void mgemm_wide_kernel(
    const ushort* __restrict__ A, const ushort* __restrict__ W,
    const float* __restrict__ bias, ushort* __restrict__ Cb,
    int M, int N, int K)
{
    __shared__ ushort As[128 * 64];
    __shared__ ushort Bs[256 * 64];
    int t = threadIdx.x;
    int l = t & 63;
    int quad = l >> 4, l15 = l & 15;
    int r7 = l15 & 7;
    int w = t >> 6;
    int wm = (w >> 1) * 64, wn = (w & 1) * 128;
    int m0 = blockIdx.x * 128, n0 = blockIdx.y * 256;

    f32x4 z = {0.f, 0.f, 0.f, 0.f};
    f32x4 acc[4][8];
#pragma unroll
    for (int i = 0; i < 4; ++i)
#pragma unroll
        for (int j = 0; j < 8; ++j) acc[i][j] = z;

    for (int k0 = 0; k0 < K; k0 += 64) {
#pragma unroll
        for (int i = 0; i < 4; ++i) {
            int chunk = i * 256 + t;
            int r = chunk >> 3, p = chunk & 7;
            int qs = (p ^ (r & 7)) * 8;
            __builtin_amdgcn_global_load_lds(
                (const __attribute__((address_space(1))) unsigned int*)
                    (A + (size_t)(m0 + r) * K + k0 + qs),
                (__attribute__((address_space(3))) unsigned int*)(As + chunk * 8), 16, 0, 0);
        }
#pragma unroll
        for (int i = 0; i < 8; ++i) {
            int chunk = i * 256 + t;
            int r = chunk >> 3, p = chunk & 7;
            int qs = (p ^ (r & 7)) * 8;
            __builtin_amdgcn_global_load_lds(
                (const __attribute__((address_space(1))) unsigned int*)
                    (W + (size_t)(n0 + r) * K + k0 + qs),
                (__attribute__((address_space(3))) unsigned int*)(Bs + chunk * 8), 16, 0, 0);
        }
        __syncthreads();
#pragma unroll
        for (int kk = 0; kk < 2; ++kk) {
            int off = ((kk * 4 + quad) ^ r7) * 8;
            s8v af[4];
#pragma unroll
            for (int i = 0; i < 4; ++i)
                af[i] = *(const s8v*)(As + (wm + i * 16 + l15) * 64 + off);
#pragma unroll
            for (int ni = 0; ni < 8; ++ni) {
                s8v bfv = *(const s8v*)(Bs + (wn + ni * 16 + l15) * 64 + off);
#pragma unroll
                for (int mi = 0; mi < 4; ++mi)
                    acc[mi][ni] = __builtin_amdgcn_mfma_f32_16x16x32_bf16(
                        af[mi], bfv, acc[mi][ni], 0, 0, 0);
            }
        }
        __syncthreads();
    }

#pragma unroll
    for (int ni = 0; ni < 8; ++ni) {
        int n = n0 + wn + ni * 16 + l15;
        float bi = bias[n];
#pragma unroll
        for (int mi = 0; mi < 4; ++mi) {
#pragma unroll
            for (int r = 0; r < 4; ++r) {
                int m = m0 + wm + mi * 16 + quad * 4 + r;
                float v = fmaxf(acc[mi][ni][r] + bi, 0.f);
                Cb[(size_t)m * N + n] = f2bf(v);
            }
        }
    }
}

// ---------------------------------------------------------------------------
// 64x64-tile, BK=64, mod-8 XOR swizzle. ASD: fused GAT logits.
// (GAT layers 1,2)
// ---------------------------------------------------------------------------
template<bool ASD>
__global__ __launch_bounds__(256) void mgemm64_kernel(
    const ushort* __restrict__ A, const ushort* __restrict__ W,
    ushort* __restrict__ Cb,
    const float* __restrict__ atts, const float* __restrict__ attd,
    float* __restrict__ a_s, float* __restrict__ a_d, int M, int N, int K)
{
    __shared__ ushort As[64 * 64];
    __shared__ ushort Bs[64 * 64];
    int t = threadIdx.x;
    int l = t & 63;
    int quad = l >> 4, l15 = l & 15;
    int r7 = l15 & 7;
    int w = t >> 6;
    int wm = (w >> 1) * 32, wn = (w & 1) * 32;
    int m0 = blockIdx.x * 64, n0 = blockIdx.y * 64;

    f32x4 z = {0.f, 0.f, 0.f, 0.f};
    f32x4 acc[2][2];
#pragma unroll
    for (int i = 0; i < 2; ++i)
#pragma unroll
        for (int j = 0; j < 2; ++j) acc[i][j] = z;

    for (int k0 = 0; k0 < K; k0 += 64) {
#pragma unroll
        for (int i = 0; i < 2; ++i) {
            int chunk = i * 256 + t;
            int r = chunk >> 3, p = chunk & 7;
            int qs = (p ^ (r & 7)) * 8;
            __builtin_amdgcn_global_load_lds(
                (const __attribute__((address_space(1))) unsigned int*)
                    (A + (size_t)(m0 + r) * K + k0 + qs),
                (__attribute__((address_space(3))) unsigned int*)(As + chunk * 8), 16, 0, 0);
            __builtin_amdgcn_global_load_lds(
                (const __attribute__((address_space(1))) unsigned int*)
                    (W + (size_t)(n0 + r) * K + k0 + qs),
                (__attribute__((address_space(3))) unsigned int*)(Bs + chunk * 8), 16, 0, 0);
        }
        __syncthreads();
#pragma unroll
        for (int kk = 0; kk < 2; ++kk) {
            s8v af[2], bfv[2];
            int off = ((kk * 4 + quad) ^ r7) * 8;
#pragma unroll
            for (int i = 0; i < 2; ++i) {
                af[i]  = *(const s8v*)(As + (wm + i * 16 + l15) * 64 + off);
                bfv[i] = *(const s8v*)(Bs + (wn + i * 16 + l15) * 64 + off);
            }
#pragma unroll
            for (int mi = 0; mi < 2; ++mi)
#pragma unroll
                for (int ni = 0; ni < 2; ++ni)
                    acc[mi][ni] = __builtin_amdgcn_mfma_f32_16x16x32_bf16(
                        af[mi], bfv[ni], acc[mi][ni], 0, 0, 0);
        }
        __syncthreads();
    }

#pragma unroll
    for (int mi = 0; mi < 2; ++mi) {
#pragma unroll
        for (int ni = 0; ni < 2; ++ni) {
            int n = n0 + wn + ni * 16 + l15;
#pragma unroll
            for (int r = 0; r < 4; ++r) {
                int m = m0 + wm + mi * 16 + quad * 4 + r;
                Cb[(size_t)m * N + n] = f2bf(acc[mi][ni][r]);
            }
        }
    }

    if (ASD) {
        int head = ((n0 + wn) >> 5) & 7;
        float as0 = atts[head * 32 + l15];
        float as1 = atts[head * 32 + 16 + l15];
        float ad0 = attd[head * 32 + l15];
        float ad1 = attd[head * 32 + 16 + l15];
#pragma unroll
        for (int mi = 0; mi < 2; ++mi)
#pragma unroll
            for (int r = 0; r < 4; ++r) {
                float sp = acc[mi][0][r] * as0 + acc[mi][1][r] * as1;
                float dp = acc[mi][0][r] * ad0 + acc[mi][1][r] * ad1;
#pragma unroll
                for (int off = 1; off < 16; off <<= 1) {
                    sp += __shfl_xor(sp, off);
                    dp += __shfl_xor(dp, off);
                }
                if (l15 == 0) {
                    int m = m0 + wm + mi * 16 + quad * 4 + r;
                    a_s[m * 8 + head] = sp;
                    a_d[m * 8 + head] = dp;
                }
            }
    }
}

// ---------------------------------------------------------------------------
// Fused GAT-L0 GEMM (+ASD logits) AND padded-CSR scatter in one dispatch.
// ---------------------------------------------------------------------------
__global__ __launch_bounds__(256) void gemm0_scatter_kernel(
    const ushort* __restrict__ A, const ushort* __restrict__ W,
    ushort* __restrict__ Cb,
    const float* __restrict__ atts, const float* __restrict__ attd,
    float* __restrict__ a_s, float* __restrict__ a_d,
    const int* __restrict__ ei, int* __restrict__ deg, int* __restrict__ col)
{
    __shared__ ushort As[64 * 64];
    __shared__ ushort Bs[64 * 64];
    int t = threadIdx.x;

    if (blockIdx.x >= 512) {
        int e = (blockIdx.x - 512) * 256 + t;
        if (e < EE + NN) {
            int s, d;
            if (e < EE) { s = ei[e]; d = ei[EE + e]; } else { s = e - EE; d = s; }
            int slot = atomicAdd(&deg[d], 1);
            col[(d << 7) + slot] = s;
        }
        return;
    }

    int l = t & 63;
    int quad = l >> 4, l15 = l & 15;
    int r7 = l15 & 7;
    int w = t >> 6;
    int wm = (w >> 1) * 32, wn = (w & 1) * 32;
    int m0 = (blockIdx.x & 127) * 64, n0 = (blockIdx.x >> 7) * 64;
    const int K = 64;

    f32x4 z = {0.f, 0.f, 0.f, 0.f};
    f32x4 acc[2][2];
#pragma unroll
    for (int i = 0; i < 2; ++i)
#pragma unroll
        for (int j = 0; j < 2; ++j) acc[i][j] = z;

#pragma unroll
    for (int i = 0; i < 2; ++i) {
        int chunk = i * 256 + t;
        int r = chunk >> 3, p = chunk & 7;
        int qs = (p ^ (r & 7)) * 8;
        __builtin_amdgcn_global_load_lds(
            (const __attribute__((address_space(1))) unsigned int*)
                (A + (size_t)(m0 + r) * K + qs),
            (__attribute__((address_space(3))) unsigned int*)(As + chunk * 8), 16, 0, 0);
        __builtin_amdgcn_global_load_lds(
            (const __attribute__((address_space(1))) unsigned int*)
                (W + (size_t)(n0 + r) * K + qs),
            (__attribute__((address_space(3))) unsigned int*)(Bs + chunk * 8), 16, 0, 0);
    }
    __syncthreads();
#pragma unroll
    for (int kk = 0; kk < 2; ++kk) {
        s8v af[2], bfv[2];
        int off = ((kk * 4 + quad) ^ r7) * 8;
#pragma unroll
        for (int i = 0; i < 2; ++i) {
            af[i]  = *(const s8v*)(As + (wm + i * 16 + l15) * 64 + off);
            bfv[i] = *(const s8v*)(Bs + (wn + i * 16 + l15) * 64 + off);
        }
#pragma unroll
        for (int mi = 0; mi < 2; ++mi)
#pragma unroll
            for (int ni = 0; ni < 2; ++ni)
                acc[mi][ni] = __builtin_amdgcn_mfma_f32_16x16x32_bf16(
                    af[mi], bfv[ni], acc[mi][ni], 0, 0, 0);
    }

#pragma unroll
    for (int mi = 0; mi < 2; ++mi) {
#pragma unroll
        for (int ni = 0; ni < 2; ++ni) {
            int n = n0 + wn + ni * 16 + l15;
#pragma unroll
            for (int r = 0; r < 4; ++r) {
                int m = m0 + wm + mi * 16 + quad * 4 + r;
                Cb[(size_t)m * DD + n] = f2bf(acc[mi][ni][r]);
            }
        }
    }

    {
        int head = ((n0 + wn) >> 5) & 7;
        float as0 = atts[head * 32 + l15];
        float as1 = atts[head * 32 + 16 + l15];
        float ad0 = attd[head * 32 + l15];
        float ad1 = attd[head * 32 + 16 + l15];
#pragma unroll
        for (int mi = 0; mi < 2; ++mi)
#pragma unroll
            for (int r = 0; r < 4; ++r) {
                float sp = acc[mi][0][r] * as0 + acc[mi][1][r] * as1;
                float dp = acc[mi][0][r] * ad0 + acc[mi][1][r] * ad1;
#pragma unroll
                for (int off = 1; off < 16; off <<= 1) {
                    sp += __shfl_xor(sp, off);
                    dp += __shfl_xor(dp, off);
                }
                if (l15 == 0) {
                    int m = m0 + wm + mi * 16 + quad * 4 + r;
                    a_s[m * 8 + head] = sp;
                    a_d[m * 8 + head] = dp;
                }
            }
    }
}

// ---------------------------------------------------------------------------
// Fused GEMM + bias + residual + LayerNorm (+ optional pred head).
// v2: tile = 32 rows x full 256 cols; 512 threads (2 row-halves x 4 col-waves);
// BK=64; grid M/32 = 256 blocks. Halves Bs weight re-staging vs 16-row tile.
// ---------------------------------------------------------------------------
template<bool PRED>
__global__ __launch_bounds__(512) void mgemm_ln_kernel(
    const ushort* __restrict__ A, const ushort* __restrict__ W,
    const float* __restrict__ bias, const float* __restrict__ res,
    const float* __restrict__ lnw, const float* __restrict__ lnbb,
    float* __restrict__ Xf, ushort* __restrict__ Xb,
    const float* __restrict__ pw, const float* __restrict__ pb,
    float* __restrict__ pout, int M, int K)
{
    __shared__ ushort As[32 * 64];
    __shared__ ushort Bs[256 * 64];
    __shared__ float red[2][4][32];
    __shared__ float predred[4][32][3];

    int t = threadIdx.x;
    int l = t & 63;
    int quad = l >> 4, l15 = l & 15;
    int r7 = l15 & 7;
    int w = t >> 6;            // 0..7
    int mh = w >> 2;           // row half 0/1 (16 rows each)
    int cw = w & 3;            // col wave 0..3
    int n0w = cw * 64;
    int m0 = blockIdx.x * 32;

    f32x4 z = {0.f, 0.f, 0.f, 0.f};
    f32x4 acc[4];
#pragma unroll
    for (int i = 0; i < 4; ++i) acc[i] = z;

    for (int k0 = 0; k0 < K; k0 += 64) {
#pragma unroll
        for (int i = 0; i < 4; ++i) {
            int chunk = i * 512 + t;
            int r = chunk >> 3, p = chunk & 7;
            int qs = (p ^ (r & 7)) * 8;
            __builtin_amdgcn_global_load_lds(
                (const __attribute__((address_space(1))) unsigned int*)
                    (W + (size_t)r * K + k0 + qs),
                (__attribute__((address_space(3))) unsigned int*)(Bs + chunk * 8), 16, 0, 0);
        }
        if (t < 256) {
            int r = t >> 3, p = t & 7;
            int qs = (p ^ (r & 7)) * 8;
            __builtin_amdgcn_global_load_lds(
                (const __attribute__((address_space(1))) unsigned int*)
                    (A + (size_t)(m0 + r) * K + k0 + qs),
                (__attribute__((address_space(3))) unsigned int*)(As + t * 8), 16, 0, 0);
        }
        __syncthreads();
#pragma unroll
        for (int kk = 0; kk < 2; ++kk) {
            int off = ((kk * 4 + quad) ^ r7) * 8;
            s8v af = *(const s8v*)(As + (mh * 16 + l15) * 64 + off);
#pragma unroll
            for (int ni = 0; ni < 4; ++ni) {
                s8v bfv = *(const s8v*)(Bs + (n0w + ni * 16 + l15) * 64 + off);
                acc[ni] = __builtin_amdgcn_mfma_f32_16x16x32_bf16(af, bfv, acc[ni], 0, 0, 0);
            }
        }
        __syncthreads();
    }

    float v[4][4];
#pragma unroll
    for (int ni = 0; ni < 4; ++ni) {
        int n = n0w + ni * 16 + l15;
        float bi = bias[n];
#pragma unroll
        for (int r = 0; r < 4; ++r) {
            int m = m0 + mh * 16 + quad * 4 + r;
            v[ni][r] = acc[ni][r] + bi + res[(size_t)m * DD + n];
        }
    }
    float s1[4], s2[4];
#pragma unroll
    for (int r = 0; r < 4; ++r) {
        s1[r] = 0.f; s2[r] = 0.f;
#pragma unroll
        for (int ni = 0; ni < 4; ++ni) { s1[r] += v[ni][r]; s2[r] += v[ni][r] * v[ni][r]; }
#pragma unroll
        for (int off = 1; off < 16; off <<= 1) {
            s1[r] += __shfl_xor(s1[r], off);
            s2[r] += __shfl_xor(s2[r], off);
        }
    }
    if (l15 == 0)
#pragma unroll
        for (int r = 0; r < 4; ++r) {
            int row = mh * 16 + quad * 4 + r;
            red[0][cw][row] = s1[r];
            red[1][cw][row] = s2[r];
        }
    __syncthreads();
    float mu[4], rstd[4];
#pragma unroll
    for (int r = 0; r < 4; ++r) {
        int row = mh * 16 + quad * 4 + r;
        float S1 = red[0][0][row] + red[0][1][row] + red[0][2][row] + red[0][3][row];
        float S2 = red[1][0][row] + red[1][1][row] + red[1][2][row] + red[1][3][row];
        mu[r] = S1 * (1.f / 256.f);
        float var = S2 * (1.f / 256.f) - mu[r] * mu[r];
        rstd[r] = rsqrtf(fmaxf(var, 0.f) + 1e-5f);
    }

    float ov[4][4];
#pragma unroll
    for (int ni = 0; ni < 4; ++ni) {
        int n = n0w + ni * 16 + l15;
        float wl = lnw[n], bl = lnbb[n];
#pragma unroll
        for (int r = 0; r < 4; ++r)
            ov[ni][r] = (v[ni][r] - mu[r]) * rstd[r] * wl + bl;
    }

    if (PRED) {
        float ps[3][4] = {};
#pragma unroll
        for (int ni = 0; ni < 4; ++ni) {
            int n = n0w + ni * 16 + l15;
            float w0 = pw[n], w1 = pw[DD + n], w2 = pw[2 * DD + n];
#pragma unroll
            for (int r = 0; r < 4; ++r) {
                ps[0][r] += ov[ni][r] * w0;
                ps[1][r] += ov[ni][r] * w1;
                ps[2][r] += ov[ni][r] * w2;
            }
        }
#pragma unroll
        for (int o3 = 0; o3 < 3; ++o3)
#pragma unroll
            for (int r = 0; r < 4; ++r)
#pragma unroll
                for (int off = 1; off < 16; off <<= 1)
                    ps[o3][r] += __shfl_xor(ps[o3][r], off);
        if (l15 == 0)
#pragma unroll
            for (int o3 = 0; o3 < 3; ++o3)
#pragma unroll
                for (int r = 0; r < 4; ++r)
                    predred[cw][mh * 16 + quad * 4 + r][o3] = ps[o3][r];
        __syncthreads();
        if (t < 96) {
            int row = t / 3, o3 = t % 3;
            float s = predred[0][row][o3] + predred[1][row][o3]
                    + predred[2][row][o3] + predred[3][row][o3] + pb[o3];
            pout[(size_t)(m0 + row) * 3 + o3] = s;
        }
    } else {
#pragma unroll
        for (int ni = 0; ni < 4; ++ni) {
            int n = n0w + ni * 16 + l15;
#pragma unroll
            for (int r = 0; r < 4; ++r) {
                int m = m0 + mh * 16 + quad * 4 + r;
                Xf[(size_t)m * DD + n] = ov[ni][r];
                Xb[(size_t)m * DD + n] = f2bf(ov[ni][r]);
            }
        }
    }
}

// ---------------------------------------------------------------------------
// qkv GEMM, 64x64 tile BK=64 (grid 128x12), fused re-layout epilogue.
// ---------------------------------------------------------------------------
__global__ __launch_bounds__(256) void mgemm_qkv_kernel(
    const ushort* __restrict__ A, const ushort* __restrict__ W,
    const float* __restrict__ bias,
    ushort* __restrict__ Qb, ushort* __restrict__ Kb, ushort* __restrict__ Vt,
    int M, int K)
{
    __shared__ ushort As[64 * 64];
    __shared__ ushort Bs[64 * 64];
    int t = threadIdx.x;
    int l = t & 63;
    int quad = l >> 4, l15 = l & 15;
    int r7 = l15 & 7;
    int w = t >> 6;
    int wm = (w >> 1) * 32, wn = (w & 1) * 32;
    int m0 = blockIdx.x * 64, n0 = blockIdx.y * 64;

    f32x4 z = {0.f, 0.f, 0.f, 0.f};
    f32x4 acc[2][2];
#pragma unroll
    for (int i = 0; i < 2; ++i)
#pragma unroll
        for (int j = 0; j < 2; ++j) acc[i][j] = z;

    for (int k0 = 0; k0 < K; k0 += 64) {
#pragma unroll
        for (int i = 0; i < 2; ++i) {
            int chunk = i * 256 + t;
            int r = chunk >> 3, p = chunk & 7;
            int qs = (p ^ (r & 7)) * 8;
            __builtin_amdgcn_global_load_lds(
                (const __attribute__((address_space(1))) unsigned int*)
                    (A + (size_t)(m0 + r) * K + k0 + qs),
                (__attribute__((address_space(3))) unsigned int*)(As + chunk * 8), 16, 0, 0);
            __builtin_amdgcn_global_load_lds(
                (const __attribute__((address_space(1))) unsigned int*)
                    (W + (size_t)(n0 + r) * K + k0 + qs),
                (__attribute__((address_space(3))) unsigned int*)(Bs + chunk * 8), 16, 0, 0);
        }
        __syncthreads();
#pragma unroll
        for (int kk = 0; kk < 2; ++kk) {
            s8v af[2], bfv[2];
            int off = ((kk * 4 + quad) ^ r7) * 8;
#pragma unroll
            for (int i = 0; i < 2; ++i) {
                af[i]  = *(const s8v*)(As + (wm + i * 16 + l15) * 64 + off);
                bfv[i] = *(const s8v*)(Bs + (wn + i * 16 + l15) * 64 + off);
            }
#pragma unroll
            for (int mi = 0; mi < 2; ++mi)
#pragma unroll
                for (int ni = 0; ni < 2; ++ni)
                    acc[mi][ni] = __builtin_amdgcn_mfma_f32_16x16x32_bf16(
                        af[mi], bfv[ni], acc[mi][ni], 0, 0, 0);
        }
        __syncthreads();
    }

#pragma unroll
    for (int mi = 0; mi < 2; ++mi) {
#pragma unroll
        for (int ni = 0; ni < 2; ++ni) {
            int n = n0 + wn + ni * 16 + l15;
            int sec = n >> 8, hc = n & 255;
            int hh = hc >> 5, c = hc & 31;
            float bv = bias[n];
#pragma unroll
            for (int r = 0; r < 4; ++r) {
                int m = m0 + wm + mi * 16 + quad * 4 + r;
                float v = acc[mi][ni][r] + bv;
                int b = m >> 10, ll2 = m & 1023;
                int bh = b * 8 + hh;
                if (sec == 0)
                    Qb[(size_t)bh * 32768 + ll2 * 32 + c] = f2bf(v * 0.17677669529663687f);
                else if (sec == 1)
                    Kb[(size_t)bh * 32768 + ll2 * 32 + c] = f2bf(v);
                else
                    Vt[(size_t)bh * 32768 + c * 1024 + ll2] = f2bf(v);
            }
        }
    }
}

// ---------------------------------------------------------------------------
// Merged cast kernel: all weights + x fp32->bf16, plus deg zeroing.
// ---------------------------------------------------------------------------
__global__ __launch_bounds__(256) void castall_kernel(
    const float* __restrict__ W0, const float* __restrict__ W12,
    const float* __restrict__ qkvw, const float* __restrict__ outw,
    const float* __restrict__ f1w, const float* __restrict__ f2w,
    const float* __restrict__ x,
    ushort* __restrict__ W0b, ushort* __restrict__ W12b,
    ushort* __restrict__ qkvb, ushort* __restrict__ outb,
    ushort* __restrict__ f1b, ushort* __restrict__ f2b,
    ushort* __restrict__ xb, int* __restrict__ deg)
{
    int tid = blockIdx.x * 256 + threadIdx.x;
    if (tid < 2048) *(int4*)(deg + tid * 4) = make_int4(0, 0, 0, 0);
    int e = tid * 4;
    if (e >= 3293184) return;
    const float* s; ushort* d; int off;
    if (e < 16384)        { s = W0;   d = W0b;  off = e; }
    else if (e < 147456)  { s = W12;  d = W12b; off = e - 16384; }
    else if (e < 540672)  { s = qkvw; d = qkvb; off = e - 147456; }
    else if (e < 671744)  { s = outw; d = outb; off = e - 540672; }
    else if (e < 1720320) { s = f1w;  d = f1b;  off = e - 671744; }
    else if (e < 2768896) { s = f2w;  d = f2b;  off = e - 1720320; }
    else                  { s = x;    d = xb;   off = e - 2768896; }
    float4 v = *(const float4*)(s + off);
    d[off + 0] = f2bf(v.x); d[off + 1] = f2bf(v.y);
    d[off + 2] = f2bf(v.z); d[off + 3] = f2bf(v.w);
}

// ---------------------------------------------------------------------------
// GAT aggregation: SINGLE pass over edges. Each lane computes its head's
// exp numerator per edge, accumulates unnormalized output AND denominator
// (redundant across the 8 lanes of a head — free), divides at the end.
// ---------------------------------------------------------------------------
template<bool WF>
__global__ __launch_bounds__(256) void gat_agg_kernel(
    const ushort* __restrict__ hlinb, const float* __restrict__ a_s,
    const float* __restrict__ a_d, const int* __restrict__ deg,
    const int* __restrict__ col, const float* __restrict__ bias,
    float* __restrict__ out, ushort* __restrict__ outb)
{
    int wid = threadIdx.x >> 6, lane = threadIdx.x & 63;
    int dst = blockIdx.x * 4 + wid;
    int start = dst << 7;
    int end = start + deg[dst];
    int myh = lane >> 3;
    float adh = a_d[(size_t)dst * HH + myh];

    float a0 = 0.f, a1 = 0.f, a2 = 0.f, a3 = 0.f, den = 0.f;
    int e = start;
    for (; e + 4 <= end; e += 4) {
        int s0 = col[e], s1 = col[e + 1], s2 = col[e + 2], s3 = col[e + 3];
        float v0 = a_s[(size_t)s0 * HH + myh] + adh;
        float v1 = a_s[(size_t)s1 * HH + myh] + adh;
        float v2 = a_s[(size_t)s2 * HH + myh] + adh;
        float v3 = a_s[(size_t)s3 * HH + myh] + adh;
        v0 = v0 > 0.f ? v0 : 0.2f * v0;
        v1 = v1 > 0.f ? v1 : 0.2f * v1;
        v2 = v2 > 0.f ? v2 : 0.2f * v2;
        v3 = v3 > 0.f ? v3 : 0.2f * v3;
        float p0 = __expf(v0), p1 = __expf(v1), p2 = __expf(v2), p3 = __expf(v3);
        den += p0 + p1 + p2 + p3;
        uint2 h0 = *(const uint2*)(hlinb + (size_t)s0 * DD + lane * 4);
        uint2 h1 = *(const uint2*)(hlinb + (size_t)s1 * DD + lane * 4);
        uint2 h2 = *(const uint2*)(hlinb + (size_t)s2 * DD + lane * 4);
        uint2 h3 = *(const uint2*)(hlinb + (size_t)s3 * DD + lane * 4);
        a0 += p0 * bf2f((ushort)(h0.x & 0xffff)) + p1 * bf2f((ushort)(h1.x & 0xffff))
            + p2 * bf2f((ushort)(h2.x & 0xffff)) + p3 * bf2f((ushort)(h3.x & 0xffff));
        a1 += p0 * bf2f((ushort)(h0.x >> 16)) + p1 * bf2f((ushort)(h1.x >> 16))
            + p2 * bf2f((ushort)(h2.x >> 16)) + p3 * bf2f((ushort)(h3.x >> 16));
        a2 += p0 * bf2f((ushort)(h0.y & 0xffff)) + p1 * bf2f((ushort)(h1.y & 0xffff))
            + p2 * bf2f((ushort)(h2.y & 0xffff)) + p3 * bf2f((ushort)(h3.y & 0xffff));
        a3 += p0 * bf2f((ushort)(h0.y >> 16)) + p1 * bf2f((ushort)(h1.y >> 16))
            + p2 * bf2f((ushort)(h2.y >> 16)) + p3 * bf2f((ushort)(h3.y >> 16));
    }
    for (; e < end; ++e) {
        int s = col[e];
        float v = a_s[(size_t)s * HH + myh] + adh;
        v = v > 0.f ? v : 0.2f * v;
        float p = __expf(v);
        den += p;
        uint2 hv = *(const uint2*)(hlinb + (size_t)s * DD + lane * 4);
        a0 += p * bf2f((ushort)(hv.x & 0xffff));
        a1 += p * bf2f((ushort)(hv.x >> 16));
        a2 += p * bf2f((ushort)(hv.y & 0xffff));
        a3 += p * bf2f((ushort)(hv.y >> 16));
    }
    float inv = 1.f / den;
    float4 bv = *(const float4*)(bias + lane * 4);
    float r0 = fmaxf(a0 * inv + bv.x, 0.f);
    float r1 = fmaxf(a1 * inv + bv.y, 0.f);
    float r2 = fmaxf(a2 * inv + bv.z, 0.f);
    float r3 = fmaxf(a3 * inv + bv.w, 0.f);
    if (WF) {
        float* op = out + (size_t)dst * DD + lane * 4;
        op[0] = r0; op[1] = r1; op[2] = r2; op[3] = r3;
    }
    ushort* ob = outb + (size_t)dst * DD + lane * 4;
    ob[0] = f2bf(r0); ob[1] = f2bf(r1); ob[2] = f2bf(r2); ob[3] = f2bf(r3);
}

// ---------------------------------------------------------------------------
// Flash-style MFMA attention: block = 128 q-rows (wave = 32 rows), 8 chunks
// of 128 keys, double-buffered K/V staging, XOR-swizzled LDS, no online max.
// v2: softmax denominator computed on the MFMA pipe via an all-ones B
// fragment (den = P·1), replacing the per-chunk shuffle-reduce chain.
// ---------------------------------------------------------------------------
__global__ __launch_bounds__(256, 2) void attn_flash_kernel(
    const ushort* __restrict__ Qb, const ushort* __restrict__ Kb,
    const ushort* __restrict__ Vt, ushort* __restrict__ outb)
{
    __shared__ ushort Ks[2][128 * 32];
    __shared__ ushort Vs[2][32 * 128];
    __shared__ ushort pw[4][32][132];

    int t = threadIdx.x;
    int w = t >> 6, lane = t & 63;
    int quad = lane >> 4, l15 = lane & 15;
    int kq = (quad ^ ((l15 >> 1) & 3)) * 8;
    int bh = blockIdx.y;
    int q0 = blockIdx.x * 128 + w * 32;
    int b = bh >> 3, h = bh & 7;

    const ushort* qbase = Qb + (size_t)bh * 32768;
    const ushort* kbase = Kb + (size_t)bh * 32768;
    const ushort* vbase = Vt + (size_t)bh * 32768;

    s8v aq0 = *(const s8v*)(qbase + (q0 + l15) * 32 + quad * 8);
    s8v aq1 = *(const s8v*)(qbase + (q0 + 16 + l15) * 32 + quad * 8);

    s8v vone;
#pragma unroll
    for (int i = 0; i < 8; ++i) vone[i] = (short)0x3F80;  // bf16 1.0

    int i0 = t, i1 = 256 + t;
    int kr0 = i0 >> 2, kcs0 = (((i0 & 3)) ^ ((kr0 >> 1) & 3)) * 8;
    int kr1 = i1 >> 2, kcs1 = (((i1 & 3)) ^ ((kr1 >> 1) & 3)) * 8;
    int vr0 = i0 >> 4, vcs0 = ((i0 & 15) ^ (vr0 & 15)) * 8;
    int vr1 = i1 >> 4, vcs1 = ((i1 & 15) ^ (vr1 & 15)) * 8;

#define STAGE(ch, bf)                                                          \
    {                                                                          \
        int j0 = (ch) * 128;                                                   \
        __builtin_amdgcn_global_load_lds(                                      \
            (const __attribute__((address_space(1))) unsigned int*)            \
                (kbase + (size_t)(j0 + kr0) * 32 + kcs0),                      \
            (__attribute__((address_space(3))) unsigned int*)(Ks[bf] + i0 * 8), 16, 0, 0); \
        __builtin_amdgcn_global_load_lds(                                      \
            (const __attribute__((address_space(1))) unsigned int*)            \
                (kbase + (size_t)(j0 + kr1) * 32 + kcs1),                      \
            (__attribute__((address_space(3))) unsigned int*)(Ks[bf] + i1 * 8), 16, 0, 0); \
        __builtin_amdgcn_global_load_lds(                                      \
            (const __attribute__((address_space(1))) unsigned int*)            \
                (vbase + (size_t)vr0 * 1024 + j0 + vcs0),                      \
            (__attribute__((address_space(3))) unsigned int*)(Vs[bf] + i0 * 8), 16, 0, 0); \
        __builtin_amdgcn_global_load_lds(                                      \
            (const __attribute__((address_space(1))) unsigned int*)            \
                (vbase + (size_t)vr1 * 1024 + j0 + vcs1),                      \
            (__attribute__((address_space(3))) unsigned int*)(Vs[bf] + i1 * 8), 16, 0, 0); \
    }

    f32x4 z = {0.f, 0.f, 0.f, 0.f};
    f32x4 o00 = z, o01 = z, o10 = z, o11 = z;
    f32x4 od0 = z, od1 = z;   // row denominators via P·1 (all 16 cols equal)

    STAGE(0, 0);
    for (int ch = 0; ch < 8; ++ch) {
        int bf = ch & 1;
        __syncthreads();
        if (ch < 7) STAGE(ch + 1, bf ^ 1);

        f32x4 s0[8], s1[8];
#pragma unroll
        for (int kk = 0; kk < 8; ++kk) {
            s8v bk = *(const s8v*)(Ks[bf] + (kk * 16 + l15) * 32 + kq);
            s0[kk] = __builtin_amdgcn_mfma_f32_16x16x32_bf16(aq0, bk, z, 0, 0, 0);
            s1[kk] = __builtin_amdgcn_mfma_f32_16x16x32_bf16(aq1, bk, z, 0, 0, 0);
        }

#pragma unroll
        for (int kk = 0; kk < 8; ++kk) {
#pragma unroll
            for (int r = 0; r < 4; ++r) {
                float p0 = __expf(s0[kk][r]);
                float p1 = __expf(s1[kk][r]);
                pw[w][quad * 4 + r][kk * 16 + l15]      = f2bf(p0);
                pw[w][16 + quad * 4 + r][kk * 16 + l15] = f2bf(p1);
            }
        }

#pragma unroll
        for (int kk = 0; kk < 4; ++kk) {
            s8v ap0 = *(const s8v*)(&pw[w][l15][kk * 32 + quad * 8]);
            s8v ap1 = *(const s8v*)(&pw[w][16 + l15][kk * 32 + quad * 8]);
            int c0 = ((kk * 4 + quad) ^ l15) * 8;
            s8v b0 = *(const s8v*)(Vs[bf] + (size_t)l15 * 128 + c0);
            s8v b1 = *(const s8v*)(Vs[bf] + (size_t)(16 + l15) * 128 + c0);
            o00 = __builtin_amdgcn_mfma_f32_16x16x32_bf16(ap0, b0, o00, 0, 0, 0);
            o01 = __builtin_amdgcn_mfma_f32_16x16x32_bf16(ap0, b1, o01, 0, 0, 0);
            o10 = __builtin_amdgcn_mfma_f32_16x16x32_bf16(ap1, b0, o10, 0, 0, 0);
            o11 = __builtin_amdgcn_mfma_f32_16x16x32_bf16(ap1, b1, o11, 0, 0, 0);
            od0 = __builtin_amdgcn_mfma_f32_16x16x32_bf16(ap0, vone, od0, 0, 0, 0);
            od1 = __builtin_amdgcn_mfma_f32_16x16x32_bf16(ap1, vone, od1, 0, 0, 0);
        }
    }
#undef STAGE

#pragma unroll
    for (int r = 0; r < 4; ++r) {
        int row0 = q0 + quad * 4 + r;
        int row1 = row0 + 16;
        float i0v = 1.f / od0[r];
        float i1v = 1.f / od1[r];
        outb[(size_t)(b * 1024 + row0) * 256 + h * 32 + l15]      = f2bf(o00[r] * i0v);
        outb[(size_t)(b * 1024 + row0) * 256 + h * 32 + 16 + l15] = f2bf(o01[r] * i0v);
        outb[(size_t)(b * 1024 + row1) * 256 + h * 32 + l15]      = f2bf(o10[r] * i1v);
        outb[(size_t)(b * 1024 + row1) * 256 + h * 32 + 16 + l15] = f2bf(o11[r] * i1v);
    }
}

// ---------------------------------------------------------------------------
extern "C" void kernel_launch(void* const* d_in, const int* in_sizes, int n_in,
                              void* d_out, int out_size, void* d_ws, size_t ws_size,
                              hipStream_t stream)
{
    const float* x        = (const float*)d_in[0];
    const int*   ei       = (const int*)d_in[1];
    const float* gat_W0   = (const float*)d_in[3];
    const float* gat_W12  = (const float*)d_in[4];
    const float* att_src  = (const float*)d_in[5];
    const float* att_dst  = (const float*)d_in[6];
    const float* gat_bias = (const float*)d_in[7];
    const float* qkv_w    = (const float*)d_in[8];
    const float* qkv_b    = (const float*)d_in[9];
    const float* out_w    = (const float*)d_in[10];
    const float* out_b    = (const float*)d_in[11];
    const float* ln1_w    = (const float*)d_in[12];
    const float* ln1_b    = (const float*)d_in[13];
    const float* ln2_w    = (const float*)d_in[14];
    const float* ln2_b    = (const float*)d_in[15];
    const float* ff1_w    = (const float*)d_in[16];
    const float* ff1_b    = (const float*)d_in[17];
    const float* ff2_w    = (const float*)d_in[18];
    const float* ff2_b    = (const float*)d_in[19];
    const float* pred_w   = (const float*)d_in[20];
    const float* pred_b   = (const float*)d_in[21];
    float* outp = (float*)d_out;

    float* ws   = (float*)d_ws;
    float* hA   = ws;                                    // [8192,256] f32
    float* hB   = ws + 2097152;                          // [8192,256] f32
    ushort* ffb  = (ushort*)(ws + 4194304);              // [8192,2048] bf16
    ushort* Qb   = (ushort*)(ws + 12582912);             // [64][1024][32]
    ushort* Kb   = (ushort*)(ws + 13631488);
    ushort* Vt   = (ushort*)(ws + 14680064);             // [64][32][1024]
    ushort* attnb= (ushort*)(ws + 15728640);             // [8192,256] bf16
    ushort* lnb  = (ushort*)(ws + 16777216);             // [8192,256] bf16
    ushort* hBb  = (ushort*)(ws + 17825792);             // [8192,256] bf16
    ushort* xb   = (ushort*)(ws + 18874368);             // [8192,64] bf16
    ushort* wbase= (ushort*)(ws + 19136512);
    ushort* W0b    = wbase;
    ushort* W12b   = wbase + 16384;
    ushort* qkv_wb = wbase + 147456;
    ushort* out_wb = wbase + 540672;
    ushort* ff1_wb = wbase + 671744;
    ushort* ff2_wb = wbase + 1720320;
    float* a_s  = ws + 20520960;
    float* a_d  = ws + 20586496;
    int*   deg  = (int*)(ws + 20652032);                 // 8192 ints
    ushort* hAb    = (ushort*)(ws + 21000192);           // [8192,256] bf16
    int*   col  = (int*)(ws + 30437376);                 // [8192*128] padded CSR

    // ---- merged casts + deg zero ----
    castall_kernel<<<3216, 256, 0, stream>>>(
        gat_W0, gat_W12, qkv_w, out_w, ff1_w, ff2_w, x,
        W0b, W12b, qkv_wb, out_wb, ff1_wb, ff2_wb, xb, deg);

    // ---- GAT L0 GEMM + padded-CSR scatter (one dispatch) ----
    gemm0_scatter_kernel<<<1568, 256, 0, stream>>>(
        xb, W0b, hAb, att_src, att_dst, a_s, a_d, ei, deg, col);
    gat_agg_kernel<false><<<2048, 256, 0, stream>>>(
        hAb, a_s, a_d, deg, col, gat_bias, nullptr, hBb);

    // ---- GAT layers 1,2 ----
    for (int l = 0; l < 2; ++l) {
        mgemm64_kernel<true><<<dim3(128, 4), 256, 0, stream>>>(
            hBb, W12b + (size_t)l * DD * DD, hAb,
            att_src + (l + 1) * 256, att_dst + (l + 1) * 256, a_s, a_d, NN, DD, DD);
        if (l == 0)
            gat_agg_kernel<false><<<2048, 256, 0, stream>>>(
                hAb, a_s, a_d, deg, col, gat_bias + 256, nullptr, hBb);
        else
            gat_agg_kernel<true><<<2048, 256, 0, stream>>>(
                hAb, a_s, a_d, deg, col, gat_bias + 512, hB, hBb);
    }

    // ---- Transformer layers (x: fp32 in hB, bf16 in hBb at loop top) ----
    for (int l = 0; l < 2; ++l) {
        mgemm_qkv_kernel<<<dim3(128, 12), 256, 0, stream>>>(
            hBb, qkv_wb + (size_t)l * 768 * DD, qkv_b + l * 768, Qb, Kb, Vt, NN, DD);
        attn_flash_kernel<<<dim3(8, 64), 256, 0, stream>>>(Qb, Kb, Vt, attnb);
        // fused out-proj + bias + residual(hB) + LN1 -> hA (fp32) + lnb (bf16)
        mgemm_ln_kernel<false><<<256, 512, 0, stream>>>(
            attnb, out_wb + (size_t)l * DD * DD, out_b + l * DD, hB,
            ln1_w + l * DD, ln1_b + l * DD, hA, lnb,
            nullptr, nullptr, nullptr, NN, DD);
        mgemm_wide_kernel<<<dim3(64, 8), 256, 0, stream>>>(
            lnb, ff1_wb + (size_t)l * DFFN * DD, ff1_b + l * DFFN, ffb, NN, DFFN, DD);
        if (l == 0) {
            mgemm_ln_kernel<false><<<256, 512, 0, stream>>>(
                ffb, ff2_wb, ff2_b, hA,
                ln2_w, ln2_b, hB, hBb,
                nullptr, nullptr, nullptr, NN, DFFN);
        } else {
            mgemm_ln_kernel<true><<<256, 512, 0, stream>>>(
                ffb, ff2_wb + (size_t)DD * DFFN, ff2_b + DD, hA,
                ln2_w + DD, ln2_b + DD, nullptr, nullptr,
                pred_w, pred_b, outp, NN, DFFN);
        }
    }
}

// Round 3
// 380.979 us; speedup vs baseline: 1.0159x; 1.0122x over previous
//
#include <hip/hip_runtime.h>
#include <hip/hip_bf16.h>

#define NN 8192
#define EE 262144
#define BB 8
#define LL 1024
#define HH 8
#define DD 256
#define DFFN 2048

typedef short s8v __attribute__((ext_vector_type(8)));
typedef float f32x4 __attribute__((ext_vector_type(4)));
typedef unsigned short ushort;

__device__ inline ushort f2bf(float f) {
    unsigned u = __float_as_uint(f);
    u = (u + 0x7fffu + ((u >> 16) & 1u)) >> 16;
    return (ushort)u;
}
__device__ inline float bf2f(ushort u) {
    return __uint_as_float(((unsigned)u) << 16);
}

// ---------------------------------------------------------------------------
// ff1 GEMM: 128x128 tile, BK=64, double-buffered LDS with counted-vmcnt
// 2-phase prefetch (T3/T4 min recipe). bias+relu+bf16 out. Grid (M/128,N/128).
// LDS = 2*(16+16) KB = 64 KB -> 2 blocks/CU.
// ---------------------------------------------------------------------------
__global__ __launch_bounds__(256) void mgemm_ff1_kernel(
    const ushort* __restrict__ A, const ushort* __restrict__ W,
    const float* __restrict__ bias, ushort* __restrict__ Cb,
    int M, int N, int K)
{
    __shared__ ushort As[2][128 * 64];
    __shared__ ushort Bs[2][128 * 64];
    int t = threadIdx.x;
    int l = t & 63;
    int quad = l >> 4, l15 = l & 15;
    int r7 = l15 & 7;
    int w = t >> 6;
    int wm = (w >> 1) * 64, wn = (w & 1) * 64;
    int m0 = blockIdx.x * 128, n0 = blockIdx.y * 128;

    // per-thread staging offsets (loop-invariant)
    int goffA[4], goffB[4], lo[4];
#pragma unroll
    for (int i = 0; i < 4; ++i) {
        int chunk = i * 256 + t;
        int r = chunk >> 3, p = chunk & 7;
        int qs = (p ^ (r & 7)) * 8;
        goffA[i] = (m0 + r) * K + qs;
        goffB[i] = (n0 + r) * K + qs;
        lo[i] = chunk * 8;
    }

#define STAGE_F(k0, bf)                                                         \
    {                                                                           \
        _Pragma("unroll")                                                       \
        for (int i = 0; i < 4; ++i) {                                           \
            __builtin_amdgcn_global_load_lds(                                   \
                (const __attribute__((address_space(1))) unsigned int*)         \
                    (A + goffA[i] + (k0)),                                      \
                (__attribute__((address_space(3))) unsigned int*)(&As[bf][0] + lo[i]), 16, 0, 0); \
            __builtin_amdgcn_global_load_lds(                                   \
                (const __attribute__((address_space(1))) unsigned int*)         \
                    (W + goffB[i] + (k0)),                                      \
                (__attribute__((address_space(3))) unsigned int*)(&Bs[bf][0] + lo[i]), 16, 0, 0); \
        }                                                                       \
    }

    f32x4 z = {0.f, 0.f, 0.f, 0.f};
    f32x4 acc[4][4];
#pragma unroll
    for (int i = 0; i < 4; ++i)
#pragma unroll
        for (int j = 0; j < 4; ++j) acc[i][j] = z;

    int nt = K >> 6;
    STAGE_F(0, 0);
    for (int ks = 0; ks < nt; ++ks) {
        int cur = ks & 1;
        if (ks + 1 < nt) {
            STAGE_F((ks + 1) << 6, cur ^ 1);
            asm volatile("s_waitcnt vmcnt(8)" ::: "memory");
        } else {
            asm volatile("s_waitcnt vmcnt(0)" ::: "memory");
        }
        __builtin_amdgcn_s_barrier();
        __builtin_amdgcn_sched_barrier(0);
#pragma unroll
        for (int kk = 0; kk < 2; ++kk) {
            int off = ((kk * 4 + quad) ^ r7) * 8;
            s8v af[4], bfv[4];
#pragma unroll
            for (int i = 0; i < 4; ++i) {
                af[i]  = *(const s8v*)(&As[cur][0] + (wm + i * 16 + l15) * 64 + off);
                bfv[i] = *(const s8v*)(&Bs[cur][0] + (wn + i * 16 + l15) * 64 + off);
            }
#pragma unroll
            for (int mi = 0; mi < 4; ++mi)
#pragma unroll
                for (int ni = 0; ni < 4; ++ni)
                    acc[mi][ni] = __builtin_amdgcn_mfma_f32_16x16x32_bf16(
                        af[mi], bfv[ni], acc[mi][ni], 0, 0, 0);
        }
        __builtin_amdgcn_sched_barrier(0);
        __builtin_amdgcn_s_barrier();
    }
#undef STAGE_F

#pragma unroll
    for (int mi = 0; mi < 4; ++mi) {
#pragma unroll
        for (int ni = 0; ni < 4; ++ni) {
            int n = n0 + wn + ni * 16 + l15;
            float bi = bias[n];
#pragma unroll
            for (int r = 0; r < 4; ++r) {
                int m = m0 + wm + mi * 16 + quad * 4 + r;
                float v = fmaxf(acc[mi][ni][r] + bi, 0.f);
                Cb[(size_t)m * N + n] = f2bf(v);
            }
        }
    }
}

// ---------------------------------------------------------------------------
// 64x64-tile, BK=64, mod-8 XOR swizzle. ASD: fused GAT logits.
// (GAT layers 1,2)
// ---------------------------------------------------------------------------
template<bool ASD>
__global__ __launch_bounds__(256) void mgemm64_kernel(
    const ushort* __restrict__ A, const ushort* __restrict__ W,
    ushort* __restrict__ Cb,
    const float* __restrict__ atts, const float* __restrict__ attd,
    float* __restrict__ a_s, float* __restrict__ a_d, int M, int N, int K)
{
    __shared__ ushort As[64 * 64];
    __shared__ ushort Bs[64 * 64];
    int t = threadIdx.x;
    int l = t & 63;
    int quad = l >> 4, l15 = l & 15;
    int r7 = l15 & 7;
    int w = t >> 6;
    int wm = (w >> 1) * 32, wn = (w & 1) * 32;
    int m0 = blockIdx.x * 64, n0 = blockIdx.y * 64;

    f32x4 z = {0.f, 0.f, 0.f, 0.f};
    f32x4 acc[2][2];
#pragma unroll
    for (int i = 0; i < 2; ++i)
#pragma unroll
        for (int j = 0; j < 2; ++j) acc[i][j] = z;

    for (int k0 = 0; k0 < K; k0 += 64) {
#pragma unroll
        for (int i = 0; i < 2; ++i) {
            int chunk = i * 256 + t;
            int r = chunk >> 3, p = chunk & 7;
            int qs = (p ^ (r & 7)) * 8;
            __builtin_amdgcn_global_load_lds(
                (const __attribute__((address_space(1))) unsigned int*)
                    (A + (size_t)(m0 + r) * K + k0 + qs),
                (__attribute__((address_space(3))) unsigned int*)(As + chunk * 8), 16, 0, 0);
            __builtin_amdgcn_global_load_lds(
                (const __attribute__((address_space(1))) unsigned int*)
                    (W + (size_t)(n0 + r) * K + k0 + qs),
                (__attribute__((address_space(3))) unsigned int*)(Bs + chunk * 8), 16, 0, 0);
        }
        __syncthreads();
#pragma unroll
        for (int kk = 0; kk < 2; ++kk) {
            s8v af[2], bfv[2];
            int off = ((kk * 4 + quad) ^ r7) * 8;
#pragma unroll
            for (int i = 0; i < 2; ++i) {
                af[i]  = *(const s8v*)(As + (wm + i * 16 + l15) * 64 + off);
                bfv[i] = *(const s8v*)(Bs + (wn + i * 16 + l15) * 64 + off);
            }
#pragma unroll
            for (int mi = 0; mi < 2; ++mi)
#pragma unroll
                for (int ni = 0; ni < 2; ++ni)
                    acc[mi][ni] = __builtin_amdgcn_mfma_f32_16x16x32_bf16(
                        af[mi], bfv[ni], acc[mi][ni], 0, 0, 0);
        }
        __syncthreads();
    }

#pragma unroll
    for (int mi = 0; mi < 2; ++mi) {
#pragma unroll
        for (int ni = 0; ni < 2; ++ni) {
            int n = n0 + wn + ni * 16 + l15;
#pragma unroll
            for (int r = 0; r < 4; ++r) {
                int m = m0 + wm + mi * 16 + quad * 4 + r;
                Cb[(size_t)m * N + n] = f2bf(acc[mi][ni][r]);
            }
        }
    }

    if (ASD) {
        int head = ((n0 + wn) >> 5) & 7;
        float as0 = atts[head * 32 + l15];
        float as1 = atts[head * 32 + 16 + l15];
        float ad0 = attd[head * 32 + l15];
        float ad1 = attd[head * 32 + 16 + l15];
#pragma unroll
        for (int mi = 0; mi < 2; ++mi)
#pragma unroll
            for (int r = 0; r < 4; ++r) {
                float sp = acc[mi][0][r] * as0 + acc[mi][1][r] * as1;
                float dp = acc[mi][0][r] * ad0 + acc[mi][1][r] * ad1;
#pragma unroll
                for (int off = 1; off < 16; off <<= 1) {
                    sp += __shfl_xor(sp, off);
                    dp += __shfl_xor(dp, off);
                }
                if (l15 == 0) {
                    int m = m0 + wm + mi * 16 + quad * 4 + r;
                    a_s[m * 8 + head] = sp;
                    a_d[m * 8 + head] = dp;
                }
            }
    }
}

// ---------------------------------------------------------------------------
// Fused GAT-L0 GEMM (+ASD logits) AND padded-CSR scatter in one dispatch.
// ---------------------------------------------------------------------------
__global__ __launch_bounds__(256) void gemm0_scatter_kernel(
    const ushort* __restrict__ A, const ushort* __restrict__ W,
    ushort* __restrict__ Cb,
    const float* __restrict__ atts, const float* __restrict__ attd,
    float* __restrict__ a_s, float* __restrict__ a_d,
    const int* __restrict__ ei, int* __restrict__ deg, int* __restrict__ col)
{
    __shared__ ushort As[64 * 64];
    __shared__ ushort Bs[64 * 64];
    int t = threadIdx.x;

    if (blockIdx.x >= 512) {
        int e = (blockIdx.x - 512) * 256 + t;
        if (e < EE + NN) {
            int s, d;
            if (e < EE) { s = ei[e]; d = ei[EE + e]; } else { s = e - EE; d = s; }
            int slot = atomicAdd(&deg[d], 1);
            col[(d << 7) + slot] = s;
        }
        return;
    }

    int l = t & 63;
    int quad = l >> 4, l15 = l & 15;
    int r7 = l15 & 7;
    int w = t >> 6;
    int wm = (w >> 1) * 32, wn = (w & 1) * 32;
    int m0 = (blockIdx.x & 127) * 64, n0 = (blockIdx.x >> 7) * 64;
    const int K = 64;

    f32x4 z = {0.f, 0.f, 0.f, 0.f};
    f32x4 acc[2][2];
#pragma unroll
    for (int i = 0; i < 2; ++i)
#pragma unroll
        for (int j = 0; j < 2; ++j) acc[i][j] = z;

#pragma unroll
    for (int i = 0; i < 2; ++i) {
        int chunk = i * 256 + t;
        int r = chunk >> 3, p = chunk & 7;
        int qs = (p ^ (r & 7)) * 8;
        __builtin_amdgcn_global_load_lds(
            (const __attribute__((address_space(1))) unsigned int*)
                (A + (size_t)(m0 + r) * K + qs),
            (__attribute__((address_space(3))) unsigned int*)(As + chunk * 8), 16, 0, 0);
        __builtin_amdgcn_global_load_lds(
            (const __attribute__((address_space(1))) unsigned int*)
                (W + (size_t)(n0 + r) * K + qs),
            (__attribute__((address_space(3))) unsigned int*)(Bs + chunk * 8), 16, 0, 0);
    }
    __syncthreads();
#pragma unroll
    for (int kk = 0; kk < 2; ++kk) {
        s8v af[2], bfv[2];
        int off = ((kk * 4 + quad) ^ r7) * 8;
#pragma unroll
        for (int i = 0; i < 2; ++i) {
            af[i]  = *(const s8v*)(As + (wm + i * 16 + l15) * 64 + off);
            bfv[i] = *(const s8v*)(Bs + (wn + i * 16 + l15) * 64 + off);
        }
#pragma unroll
        for (int mi = 0; mi < 2; ++mi)
#pragma unroll
            for (int ni = 0; ni < 2; ++ni)
                acc[mi][ni] = __builtin_amdgcn_mfma_f32_16x16x32_bf16(
                    af[mi], bfv[ni], acc[mi][ni], 0, 0, 0);
    }

#pragma unroll
    for (int mi = 0; mi < 2; ++mi) {
#pragma unroll
        for (int ni = 0; ni < 2; ++ni) {
            int n = n0 + wn + ni * 16 + l15;
#pragma unroll
            for (int r = 0; r < 4; ++r) {
                int m = m0 + wm + mi * 16 + quad * 4 + r;
                Cb[(size_t)m * DD + n] = f2bf(acc[mi][ni][r]);
            }
        }
    }

    {
        int head = ((n0 + wn) >> 5) & 7;
        float as0 = atts[head * 32 + l15];
        float as1 = atts[head * 32 + 16 + l15];
        float ad0 = attd[head * 32 + l15];
        float ad1 = attd[head * 32 + 16 + l15];
#pragma unroll
        for (int mi = 0; mi < 2; ++mi)
#pragma unroll
            for (int r = 0; r < 4; ++r) {
                float sp = acc[mi][0][r] * as0 + acc[mi][1][r] * as1;
                float dp = acc[mi][0][r] * ad0 + acc[mi][1][r] * ad1;
#pragma unroll
                for (int off = 1; off < 16; off <<= 1) {
                    sp += __shfl_xor(sp, off);
                    dp += __shfl_xor(dp, off);
                }
                if (l15 == 0) {
                    int m = m0 + wm + mi * 16 + quad * 4 + r;
                    a_s[m * 8 + head] = sp;
                    a_d[m * 8 + head] = dp;
                }
            }
    }
}

// ---------------------------------------------------------------------------
// Fused GEMM + bias + residual + LayerNorm (+ optional pred head).
// v3: 32 rows x 256 cols, 512 threads, double-buffered LDS with counted-vmcnt
// 2-phase prefetch (grid = 256 blocks = 1 block/CU -> pipelining is the only
// way to hide the staging drain; no other resident blocks to overlap with).
// ---------------------------------------------------------------------------
template<bool PRED>
__global__ __launch_bounds__(512) void mgemm_ln_kernel(
    const ushort* __restrict__ A, const ushort* __restrict__ W,
    const float* __restrict__ bias, const float* __restrict__ res,
    const float* __restrict__ lnw, const float* __restrict__ lnbb,
    float* __restrict__ Xf, ushort* __restrict__ Xb,
    const float* __restrict__ pw, const float* __restrict__ pb,
    float* __restrict__ pout, int M, int K)
{
    __shared__ ushort As[2][32 * 64];
    __shared__ ushort Bs[2][256 * 64];
    __shared__ float red[2][4][32];
    __shared__ float predred[4][32][3];

    int t = threadIdx.x;
    int l = t & 63;
    int quad = l >> 4, l15 = l & 15;
    int r7 = l15 & 7;
    int w = t >> 6;            // 0..7
    int mh = w >> 2;           // row half 0/1 (16 rows each)
    int cw = w & 3;            // col wave 0..3
    int n0w = cw * 64;
    int m0 = blockIdx.x * 32;

    // per-thread staging offsets (loop-invariant)
    int goffB[4], loB[4];
#pragma unroll
    for (int i = 0; i < 4; ++i) {
        int chunk = i * 512 + t;
        int r = chunk >> 3, p = chunk & 7;
        goffB[i] = r * K + (p ^ (r & 7)) * 8;
        loB[i] = chunk * 8;
    }
    int rA = t >> 3, pA = t & 7;
    int goffA = (m0 + rA) * K + (pA ^ (rA & 7)) * 8;
    int loA = t * 8;

#define STAGE_LN(k0, bf)                                                        \
    {                                                                           \
        _Pragma("unroll")                                                       \
        for (int i = 0; i < 4; ++i)                                             \
            __builtin_amdgcn_global_load_lds(                                   \
                (const __attribute__((address_space(1))) unsigned int*)         \
                    (W + goffB[i] + (k0)),                                      \
                (__attribute__((address_space(3))) unsigned int*)(&Bs[bf][0] + loB[i]), 16, 0, 0); \
        if (t < 256)                                                            \
            __builtin_amdgcn_global_load_lds(                                   \
                (const __attribute__((address_space(1))) unsigned int*)         \
                    (A + goffA + (k0)),                                         \
                (__attribute__((address_space(3))) unsigned int*)(&As[bf][0] + loA), 16, 0, 0); \
    }

    f32x4 z = {0.f, 0.f, 0.f, 0.f};
    f32x4 acc[4];
#pragma unroll
    for (int i = 0; i < 4; ++i) acc[i] = z;

    int nt = K >> 6;
    STAGE_LN(0, 0);
    for (int ks = 0; ks < nt; ++ks) {
        int cur = ks & 1;
        if (ks + 1 < nt) {
            STAGE_LN((ks + 1) << 6, cur ^ 1);
            // waves 4-7 issue 4 loads/tile, waves 0-3 issue 5; vmcnt(4) is the
            // uniform bound that guarantees the previous tile is fully landed.
            asm volatile("s_waitcnt vmcnt(4)" ::: "memory");
        } else {
            asm volatile("s_waitcnt vmcnt(0)" ::: "memory");
        }
        __builtin_amdgcn_s_barrier();
        __builtin_amdgcn_sched_barrier(0);
#pragma unroll
        for (int kk = 0; kk < 2; ++kk) {
            int off = ((kk * 4 + quad) ^ r7) * 8;
            s8v af = *(const s8v*)(&As[cur][0] + (mh * 16 + l15) * 64 + off);
#pragma unroll
            for (int ni = 0; ni < 4; ++ni) {
                s8v bfv = *(const s8v*)(&Bs[cur][0] + (n0w + ni * 16 + l15) * 64 + off);
                acc[ni] = __builtin_amdgcn_mfma_f32_16x16x32_bf16(af, bfv, acc[ni], 0, 0, 0);
            }
        }
        __builtin_amdgcn_sched_barrier(0);
        __builtin_amdgcn_s_barrier();
    }
#undef STAGE_LN

    float v[4][4];
#pragma unroll
    for (int ni = 0; ni < 4; ++ni) {
        int n = n0w + ni * 16 + l15;
        float bi = bias[n];
#pragma unroll
        for (int r = 0; r < 4; ++r) {
            int m = m0 + mh * 16 + quad * 4 + r;
            v[ni][r] = acc[ni][r] + bi + res[(size_t)m * DD + n];
        }
    }
    float s1[4], s2[4];
#pragma unroll
    for (int r = 0; r < 4; ++r) {
        s1[r] = 0.f; s2[r] = 0.f;
#pragma unroll
        for (int ni = 0; ni < 4; ++ni) { s1[r] += v[ni][r]; s2[r] += v[ni][r] * v[ni][r]; }
#pragma unroll
        for (int off = 1; off < 16; off <<= 1) {
            s1[r] += __shfl_xor(s1[r], off);
            s2[r] += __shfl_xor(s2[r], off);
        }
    }
    if (l15 == 0)
#pragma unroll
        for (int r = 0; r < 4; ++r) {
            int row = mh * 16 + quad * 4 + r;
            red[0][cw][row] = s1[r];
            red[1][cw][row] = s2[r];
        }
    __syncthreads();
    float mu[4], rstd[4];
#pragma unroll
    for (int r = 0; r < 4; ++r) {
        int row = mh * 16 + quad * 4 + r;
        float S1 = red[0][0][row] + red[0][1][row] + red[0][2][row] + red[0][3][row];
        float S2 = red[1][0][row] + red[1][1][row] + red[1][2][row] + red[1][3][row];
        mu[r] = S1 * (1.f / 256.f);
        float var = S2 * (1.f / 256.f) - mu[r] * mu[r];
        rstd[r] = rsqrtf(fmaxf(var, 0.f) + 1e-5f);
    }

    float ov[4][4];
#pragma unroll
    for (int ni = 0; ni < 4; ++ni) {
        int n = n0w + ni * 16 + l15;
        float wl = lnw[n], bl = lnbb[n];
#pragma unroll
        for (int r = 0; r < 4; ++r)
            ov[ni][r] = (v[ni][r] - mu[r]) * rstd[r] * wl + bl;
    }

    if (PRED) {
        float ps[3][4] = {};
#pragma unroll
        for (int ni = 0; ni < 4; ++ni) {
            int n = n0w + ni * 16 + l15;
            float w0 = pw[n], w1 = pw[DD + n], w2 = pw[2 * DD + n];
#pragma unroll
            for (int r = 0; r < 4; ++r) {
                ps[0][r] += ov[ni][r] * w0;
                ps[1][r] += ov[ni][r] * w1;
                ps[2][r] += ov[ni][r] * w2;
            }
        }
#pragma unroll
        for (int o3 = 0; o3 < 3; ++o3)
#pragma unroll
            for (int r = 0; r < 4; ++r)
#pragma unroll
                for (int off = 1; off < 16; off <<= 1)
                    ps[o3][r] += __shfl_xor(ps[o3][r], off);
        if (l15 == 0)
#pragma unroll
            for (int o3 = 0; o3 < 3; ++o3)
#pragma unroll
                for (int r = 0; r < 4; ++r)
                    predred[cw][mh * 16 + quad * 4 + r][o3] = ps[o3][r];
        __syncthreads();
        if (t < 96) {
            int row = t / 3, o3 = t % 3;
            float s = predred[0][row][o3] + predred[1][row][o3]
                    + predred[2][row][o3] + predred[3][row][o3] + pb[o3];
            pout[(size_t)(m0 + row) * 3 + o3] = s;
        }
    } else {
#pragma unroll
        for (int ni = 0; ni < 4; ++ni) {
            int n = n0w + ni * 16 + l15;
#pragma unroll
            for (int r = 0; r < 4; ++r) {
                int m = m0 + mh * 16 + quad * 4 + r;
                Xf[(size_t)m * DD + n] = ov[ni][r];
                Xb[(size_t)m * DD + n] = f2bf(ov[ni][r]);
            }
        }
    }
}

// ---------------------------------------------------------------------------
// qkv GEMM, 64x64 tile BK=64 (grid 128x12), fused re-layout epilogue.
// ---------------------------------------------------------------------------
__global__ __launch_bounds__(256) void mgemm_qkv_kernel(
    const ushort* __restrict__ A, const ushort* __restrict__ W,
    const float* __restrict__ bias,
    ushort* __restrict__ Qb, ushort* __restrict__ Kb, ushort* __restrict__ Vt,
    int M, int K)
{
    __shared__ ushort As[64 * 64];
    __shared__ ushort Bs[64 * 64];
    int t = threadIdx.x;
    int l = t & 63;
    int quad = l >> 4, l15 = l & 15;
    int r7 = l15 & 7;
    int w = t >> 6;
    int wm = (w >> 1) * 32, wn = (w & 1) * 32;
    int m0 = blockIdx.x * 64, n0 = blockIdx.y * 64;

    f32x4 z = {0.f, 0.f, 0.f, 0.f};
    f32x4 acc[2][2];
#pragma unroll
    for (int i = 0; i < 2; ++i)
#pragma unroll
        for (int j = 0; j < 2; ++j) acc[i][j] = z;

    for (int k0 = 0; k0 < K; k0 += 64) {
#pragma unroll
        for (int i = 0; i < 2; ++i) {
            int chunk = i * 256 + t;
            int r = chunk >> 3, p = chunk & 7;
            int qs = (p ^ (r & 7)) * 8;
            __builtin_amdgcn_global_load_lds(
                (const __attribute__((address_space(1))) unsigned int*)
                    (A + (size_t)(m0 + r) * K + k0 + qs),
                (__attribute__((address_space(3))) unsigned int*)(As + chunk * 8), 16, 0, 0);
            __builtin_amdgcn_global_load_lds(
                (const __attribute__((address_space(1))) unsigned int*)
                    (W + (size_t)(n0 + r) * K + k0 + qs),
                (__attribute__((address_space(3))) unsigned int*)(Bs + chunk * 8), 16, 0, 0);
        }
        __syncthreads();
#pragma unroll
        for (int kk = 0; kk < 2; ++kk) {
            s8v af[2], bfv[2];
            int off = ((kk * 4 + quad) ^ r7) * 8;
#pragma unroll
            for (int i = 0; i < 2; ++i) {
                af[i]  = *(const s8v*)(As + (wm + i * 16 + l15) * 64 + off);
                bfv[i] = *(const s8v*)(Bs + (wn + i * 16 + l15) * 64 + off);
            }
#pragma unroll
            for (int mi = 0; mi < 2; ++mi)
#pragma unroll
                for (int ni = 0; ni < 2; ++ni)
                    acc[mi][ni] = __builtin_amdgcn_mfma_f32_16x16x32_bf16(
                        af[mi], bfv[ni], acc[mi][ni], 0, 0, 0);
        }
        __syncthreads();
    }

#pragma unroll
    for (int mi = 0; mi < 2; ++mi) {
#pragma unroll
        for (int ni = 0; ni < 2; ++ni) {
            int n = n0 + wn + ni * 16 + l15;
            int sec = n >> 8, hc = n & 255;
            int hh = hc >> 5, c = hc & 31;
            float bv = bias[n];
#pragma unroll
            for (int r = 0; r < 4; ++r) {
                int m = m0 + wm + mi * 16 + quad * 4 + r;
                float v = acc[mi][ni][r] + bv;
                int b = m >> 10, ll2 = m & 1023;
                int bh = b * 8 + hh;
                if (sec == 0)
                    Qb[(size_t)bh * 32768 + ll2 * 32 + c] = f2bf(v * 0.17677669529663687f);
                else if (sec == 1)
                    Kb[(size_t)bh * 32768 + ll2 * 32 + c] = f2bf(v);
                else
                    Vt[(size_t)bh * 32768 + c * 1024 + ll2] = f2bf(v);
            }
        }
    }
}

// ---------------------------------------------------------------------------
// Merged cast kernel: all weights + x fp32->bf16, plus deg zeroing.
// ---------------------------------------------------------------------------
__global__ __launch_bounds__(256) void castall_kernel(
    const float* __restrict__ W0, const float* __restrict__ W12,
    const float* __restrict__ qkvw, const float* __restrict__ outw,
    const float* __restrict__ f1w, const float* __restrict__ f2w,
    const float* __restrict__ x,
    ushort* __restrict__ W0b, ushort* __restrict__ W12b,
    ushort* __restrict__ qkvb, ushort* __restrict__ outb,
    ushort* __restrict__ f1b, ushort* __restrict__ f2b,
    ushort* __restrict__ xb, int* __restrict__ deg)
{
    int tid = blockIdx.x * 256 + threadIdx.x;
    if (tid < 2048) *(int4*)(deg + tid * 4) = make_int4(0, 0, 0, 0);
    int e = tid * 4;
    if (e >= 3293184) return;
    const float* s; ushort* d; int off;
    if (e < 16384)        { s = W0;   d = W0b;  off = e; }
    else if (e < 147456)  { s = W12;  d = W12b; off = e - 16384; }
    else if (e < 540672)  { s = qkvw; d = qkvb; off = e - 147456; }
    else if (e < 671744)  { s = outw; d = outb; off = e - 540672; }
    else if (e < 1720320) { s = f1w;  d = f1b;  off = e - 671744; }
    else if (e < 2768896) { s = f2w;  d = f2b;  off = e - 1720320; }
    else                  { s = x;    d = xb;   off = e - 2768896; }
    float4 v = *(const float4*)(s + off);
    d[off + 0] = f2bf(v.x); d[off + 1] = f2bf(v.y);
    d[off + 2] = f2bf(v.z); d[off + 3] = f2bf(v.w);
}

// ---------------------------------------------------------------------------
// GAT aggregation: SINGLE pass over edges. Each lane computes its head's
// exp numerator per edge, accumulates unnormalized output AND denominator
// (redundant across the 8 lanes of a head — free), divides at the end.
// ---------------------------------------------------------------------------
template<bool WF>
__global__ __launch_bounds__(256) void gat_agg_kernel(
    const ushort* __restrict__ hlinb, const float* __restrict__ a_s,
    const float* __restrict__ a_d, const int* __restrict__ deg,
    const int* __restrict__ col, const float* __restrict__ bias,
    float* __restrict__ out, ushort* __restrict__ outb)
{
    int wid = threadIdx.x >> 6, lane = threadIdx.x & 63;
    int dst = blockIdx.x * 4 + wid;
    int start = dst << 7;
    int end = start + deg[dst];
    int myh = lane >> 3;
    float adh = a_d[(size_t)dst * HH + myh];

    float a0 = 0.f, a1 = 0.f, a2 = 0.f, a3 = 0.f, den = 0.f;
    int e = start;
    for (; e + 4 <= end; e += 4) {
        int s0 = col[e], s1 = col[e + 1], s2 = col[e + 2], s3 = col[e + 3];
        float v0 = a_s[(size_t)s0 * HH + myh] + adh;
        float v1 = a_s[(size_t)s1 * HH + myh] + adh;
        float v2 = a_s[(size_t)s2 * HH + myh] + adh;
        float v3 = a_s[(size_t)s3 * HH + myh] + adh;
        v0 = v0 > 0.f ? v0 : 0.2f * v0;
        v1 = v1 > 0.f ? v1 : 0.2f * v1;
        v2 = v2 > 0.f ? v2 : 0.2f * v2;
        v3 = v3 > 0.f ? v3 : 0.2f * v3;
        float p0 = __expf(v0), p1 = __expf(v1), p2 = __expf(v2), p3 = __expf(v3);
        den += p0 + p1 + p2 + p3;
        uint2 h0 = *(const uint2*)(hlinb + (size_t)s0 * DD + lane * 4);
        uint2 h1 = *(const uint2*)(hlinb + (size_t)s1 * DD + lane * 4);
        uint2 h2 = *(const uint2*)(hlinb + (size_t)s2 * DD + lane * 4);
        uint2 h3 = *(const uint2*)(hlinb + (size_t)s3 * DD + lane * 4);
        a0 += p0 * bf2f((ushort)(h0.x & 0xffff)) + p1 * bf2f((ushort)(h1.x & 0xffff))
            + p2 * bf2f((ushort)(h2.x & 0xffff)) + p3 * bf2f((ushort)(h3.x & 0xffff));
        a1 += p0 * bf2f((ushort)(h0.x >> 16)) + p1 * bf2f((ushort)(h1.x >> 16))
            + p2 * bf2f((ushort)(h2.x >> 16)) + p3 * bf2f((ushort)(h3.x >> 16));
        a2 += p0 * bf2f((ushort)(h0.y & 0xffff)) + p1 * bf2f((ushort)(h1.y & 0xffff))
            + p2 * bf2f((ushort)(h2.y & 0xffff)) + p3 * bf2f((ushort)(h3.y & 0xffff));
        a3 += p0 * bf2f((ushort)(h0.y >> 16)) + p1 * bf2f((ushort)(h1.y >> 16))
            + p2 * bf2f((ushort)(h2.y >> 16)) + p3 * bf2f((ushort)(h3.y >> 16));
    }
    for (; e < end; ++e) {
        int s = col[e];
        float v = a_s[(size_t)s * HH + myh] + adh;
        v = v > 0.f ? v : 0.2f * v;
        float p = __expf(v);
        den += p;
        uint2 hv = *(const uint2*)(hlinb + (size_t)s * DD + lane * 4);
        a0 += p * bf2f((ushort)(hv.x & 0xffff));
        a1 += p * bf2f((ushort)(hv.x >> 16));
        a2 += p * bf2f((ushort)(hv.y & 0xffff));
        a3 += p * bf2f((ushort)(hv.y >> 16));
    }
    float inv = 1.f / den;
    float4 bv = *(const float4*)(bias + lane * 4);
    float r0 = fmaxf(a0 * inv + bv.x, 0.f);
    float r1 = fmaxf(a1 * inv + bv.y, 0.f);
    float r2 = fmaxf(a2 * inv + bv.z, 0.f);
    float r3 = fmaxf(a3 * inv + bv.w, 0.f);
    if (WF) {
        float* op = out + (size_t)dst * DD + lane * 4;
        op[0] = r0; op[1] = r1; op[2] = r2; op[3] = r3;
    }
    ushort* ob = outb + (size_t)dst * DD + lane * 4;
    ob[0] = f2bf(r0); ob[1] = f2bf(r1); ob[2] = f2bf(r2); ob[3] = f2bf(r3);
}

// ---------------------------------------------------------------------------
// Flash-style MFMA attention: block = 128 q-rows (wave = 32 rows), 8 chunks
// of 128 keys, double-buffered K/V staging, XOR-swizzled LDS, no online max.
// Softmax denominator on the MFMA pipe via an all-ones B fragment (den = P*1).
// ---------------------------------------------------------------------------
__global__ __launch_bounds__(256, 2) void attn_flash_kernel(
    const ushort* __restrict__ Qb, const ushort* __restrict__ Kb,
    const ushort* __restrict__ Vt, ushort* __restrict__ outb)
{
    __shared__ ushort Ks[2][128 * 32];
    __shared__ ushort Vs[2][32 * 128];
    __shared__ ushort pw[4][32][132];

    int t = threadIdx.x;
    int w = t >> 6, lane = t & 63;
    int quad = lane >> 4, l15 = lane & 15;
    int kq = (quad ^ ((l15 >> 1) & 3)) * 8;
    int bh = blockIdx.y;
    int q0 = blockIdx.x * 128 + w * 32;
    int b = bh >> 3, h = bh & 7;

    const ushort* qbase = Qb + (size_t)bh * 32768;
    const ushort* kbase = Kb + (size_t)bh * 32768;
    const ushort* vbase = Vt + (size_t)bh * 32768;

    s8v aq0 = *(const s8v*)(qbase + (q0 + l15) * 32 + quad * 8);
    s8v aq1 = *(const s8v*)(qbase + (q0 + 16 + l15) * 32 + quad * 8);

    s8v vone;
#pragma unroll
    for (int i = 0; i < 8; ++i) vone[i] = (short)0x3F80;  // bf16 1.0

    int i0 = t, i1 = 256 + t;
    int kr0 = i0 >> 2, kcs0 = (((i0 & 3)) ^ ((kr0 >> 1) & 3)) * 8;
    int kr1 = i1 >> 2, kcs1 = (((i1 & 3)) ^ ((kr1 >> 1) & 3)) * 8;
    int vr0 = i0 >> 4, vcs0 = ((i0 & 15) ^ (vr0 & 15)) * 8;
    int vr1 = i1 >> 4, vcs1 = ((i1 & 15) ^ (vr1 & 15)) * 8;

#define STAGE(ch, bf)                                                          \
    {                                                                          \
        int j0 = (ch) * 128;                                                   \
        __builtin_amdgcn_global_load_lds(                                      \
            (const __attribute__((address_space(1))) unsigned int*)            \
                (kbase + (size_t)(j0 + kr0) * 32 + kcs0),                      \
            (__attribute__((address_space(3))) unsigned int*)(Ks[bf] + i0 * 8), 16, 0, 0); \
        __builtin_amdgcn_global_load_lds(                                      \
            (const __attribute__((address_space(1))) unsigned int*)            \
                (kbase + (size_t)(j0 + kr1) * 32 + kcs1),                      \
            (__attribute__((address_space(3))) unsigned int*)(Ks[bf] + i1 * 8), 16, 0, 0); \
        __builtin_amdgcn_global_load_lds(                                      \
            (const __attribute__((address_space(1))) unsigned int*)            \
                (vbase + (size_t)vr0 * 1024 + j0 + vcs0),                      \
            (__attribute__((address_space(3))) unsigned int*)(Vs[bf] + i0 * 8), 16, 0, 0); \
        __builtin_amdgcn_global_load_lds(                                      \
            (const __attribute__((address_space(1))) unsigned int*)            \
                (vbase + (size_t)vr1 * 1024 + j0 + vcs1),                      \
            (__attribute__((address_space(3))) unsigned int*)(Vs[bf] + i1 * 8), 16, 0, 0); \
    }

    f32x4 z = {0.f, 0.f, 0.f, 0.f};
    f32x4 o00 = z, o01 = z, o10 = z, o11 = z;
    f32x4 od0 = z, od1 = z;   // row denominators via P*1 (all 16 cols equal)

    STAGE(0, 0);
    for (int ch = 0; ch < 8; ++ch) {
        int bf = ch & 1;
        __syncthreads();
        if (ch < 7) STAGE(ch + 1, bf ^ 1);

        f32x4 s0[8], s1[8];
#pragma unroll
        for (int kk = 0; kk < 8; ++kk) {
            s8v bk = *(const s8v*)(Ks[bf] + (kk * 16 + l15) * 32 + kq);
            s0[kk] = __builtin_amdgcn_mfma_f32_16x16x32_bf16(aq0, bk, z, 0, 0, 0);
            s1[kk] = __builtin_amdgcn_mfma_f32_16x16x32_bf16(aq1, bk, z, 0, 0, 0);
        }

#pragma unroll
        for (int kk = 0; kk < 8; ++kk) {
#pragma unroll
            for (int r = 0; r < 4; ++r) {
                float p0 = __expf(s0[kk][r]);
                float p1 = __expf(s1[kk][r]);
                pw[w][quad * 4 + r][kk * 16 + l15]      = f2bf(p0);
                pw[w][16 + quad * 4 + r][kk * 16 + l15] = f2bf(p1);
            }
        }

#pragma unroll
        for (int kk = 0; kk < 4; ++kk) {
            s8v ap0 = *(const s8v*)(&pw[w][l15][kk * 32 + quad * 8]);
            s8v ap1 = *(const s8v*)(&pw[w][16 + l15][kk * 32 + quad * 8]);
            int c0 = ((kk * 4 + quad) ^ l15) * 8;
            s8v b0 = *(const s8v*)(Vs[bf] + (size_t)l15 * 128 + c0);
            s8v b1 = *(const s8v*)(Vs[bf] + (size_t)(16 + l15) * 128 + c0);
            o00 = __builtin_amdgcn_mfma_f32_16x16x32_bf16(ap0, b0, o00, 0, 0, 0);
            o01 = __builtin_amdgcn_mfma_f32_16x16x32_bf16(ap0, b1, o01, 0, 0, 0);
            o10 = __builtin_amdgcn_mfma_f32_16x16x32_bf16(ap1, b0, o10, 0, 0, 0);
            o11 = __builtin_amdgcn_mfma_f32_16x16x32_bf16(ap1, b1, o11, 0, 0, 0);
            od0 = __builtin_amdgcn_mfma_f32_16x16x32_bf16(ap0, vone, od0, 0, 0, 0);
            od1 = __builtin_amdgcn_mfma_f32_16x16x32_bf16(ap1, vone, od1, 0, 0, 0);
        }
    }
#undef STAGE

#pragma unroll
    for (int r = 0; r < 4; ++r) {
        int row0 = q0 + quad * 4 + r;
        int row1 = row0 + 16;
        float i0v = 1.f / od0[r];
        float i1v = 1.f / od1[r];
        outb[(size_t)(b * 1024 + row0) * 256 + h * 32 + l15]      = f2bf(o00[r] * i0v);
        outb[(size_t)(b * 1024 + row0) * 256 + h * 32 + 16 + l15] = f2bf(o01[r] * i0v);
        outb[(size_t)(b * 1024 + row1) * 256 + h * 32 + l15]      = f2bf(o10[r] * i1v);
        outb[(size_t)(b * 1024 + row1) * 256 + h * 32 + 16 + l15] = f2bf(o11[r] * i1v);
    }
}

// ---------------------------------------------------------------------------
extern "C" void kernel_launch(void* const* d_in, const int* in_sizes, int n_in,
                              void* d_out, int out_size, void* d_ws, size_t ws_size,
                              hipStream_t stream)
{
    const float* x        = (const float*)d_in[0];
    const int*   ei       = (const int*)d_in[1];
    const float* gat_W0   = (const float*)d_in[3];
    const float* gat_W12  = (const float*)d_in[4];
    const float* att_src  = (const float*)d_in[5];
    const float* att_dst  = (const float*)d_in[6];
    const float* gat_bias = (const float*)d_in[7];
    const float* qkv_w    = (const float*)d_in[8];
    const float* qkv_b    = (const float*)d_in[9];
    const float* out_w    = (const float*)d_in[10];
    const float* out_b    = (const float*)d_in[11];
    const float* ln1_w    = (const float*)d_in[12];
    const float* ln1_b    = (const float*)d_in[13];
    const float* ln2_w    = (const float*)d_in[14];
    const float* ln2_b    = (const float*)d_in[15];
    const float* ff1_w    = (const float*)d_in[16];
    const float* ff1_b    = (const float*)d_in[17];
    const float* ff2_w    = (const float*)d_in[18];
    const float* ff2_b    = (const float*)d_in[19];
    const float* pred_w   = (const float*)d_in[20];
    const float* pred_b   = (const float*)d_in[21];
    float* outp = (float*)d_out;

    float* ws   = (float*)d_ws;
    float* hA   = ws;                                    // [8192,256] f32
    float* hB   = ws + 2097152;                          // [8192,256] f32
    ushort* ffb  = (ushort*)(ws + 4194304);              // [8192,2048] bf16
    ushort* Qb   = (ushort*)(ws + 12582912);             // [64][1024][32]
    ushort* Kb   = (ushort*)(ws + 13631488);
    ushort* Vt   = (ushort*)(ws + 14680064);             // [64][32][1024]
    ushort* attnb= (ushort*)(ws + 15728640);             // [8192,256] bf16
    ushort* lnb  = (ushort*)(ws + 16777216);             // [8192,256] bf16
    ushort* hBb  = (ushort*)(ws + 17825792);             // [8192,256] bf16
    ushort* xb   = (ushort*)(ws + 18874368);             // [8192,64] bf16
    ushort* wbase= (ushort*)(ws + 19136512);
    ushort* W0b    = wbase;
    ushort* W12b   = wbase + 16384;
    ushort* qkv_wb = wbase + 147456;
    ushort* out_wb = wbase + 540672;
    ushort* ff1_wb = wbase + 671744;
    ushort* ff2_wb = wbase + 1720320;
    float* a_s  = ws + 20520960;
    float* a_d  = ws + 20586496;
    int*   deg  = (int*)(ws + 20652032);                 // 8192 ints
    ushort* hAb    = (ushort*)(ws + 21000192);           // [8192,256] bf16
    int*   col  = (int*)(ws + 30437376);                 // [8192*128] padded CSR

    // ---- merged casts + deg zero ----
    castall_kernel<<<3216, 256, 0, stream>>>(
        gat_W0, gat_W12, qkv_w, out_w, ff1_w, ff2_w, x,
        W0b, W12b, qkv_wb, out_wb, ff1_wb, ff2_wb, xb, deg);

    // ---- GAT L0 GEMM + padded-CSR scatter (one dispatch) ----
    gemm0_scatter_kernel<<<1568, 256, 0, stream>>>(
        xb, W0b, hAb, att_src, att_dst, a_s, a_d, ei, deg, col);
    gat_agg_kernel<false><<<2048, 256, 0, stream>>>(
        hAb, a_s, a_d, deg, col, gat_bias, nullptr, hBb);

    // ---- GAT layers 1,2 ----
    for (int l = 0; l < 2; ++l) {
        mgemm64_kernel<true><<<dim3(128, 4), 256, 0, stream>>>(
            hBb, W12b + (size_t)l * DD * DD, hAb,
            att_src + (l + 1) * 256, att_dst + (l + 1) * 256, a_s, a_d, NN, DD, DD);
        if (l == 0)
            gat_agg_kernel<false><<<2048, 256, 0, stream>>>(
                hAb, a_s, a_d, deg, col, gat_bias + 256, nullptr, hBb);
        else
            gat_agg_kernel<true><<<2048, 256, 0, stream>>>(
                hAb, a_s, a_d, deg, col, gat_bias + 512, hB, hBb);
    }

    // ---- Transformer layers (x: fp32 in hB, bf16 in hBb at loop top) ----
    for (int l = 0; l < 2; ++l) {
        mgemm_qkv_kernel<<<dim3(128, 12), 256, 0, stream>>>(
            hBb, qkv_wb + (size_t)l * 768 * DD, qkv_b + l * 768, Qb, Kb, Vt, NN, DD);
        attn_flash_kernel<<<dim3(8, 64), 256, 0, stream>>>(Qb, Kb, Vt, attnb);
        // fused out-proj + bias + residual(hB) + LN1 -> hA (fp32) + lnb (bf16)
        mgemm_ln_kernel<false><<<256, 512, 0, stream>>>(
            attnb, out_wb + (size_t)l * DD * DD, out_b + l * DD, hB,
            ln1_w + l * DD, ln1_b + l * DD, hA, lnb,
            nullptr, nullptr, nullptr, NN, DD);
        mgemm_ff1_kernel<<<dim3(64, 16), 256, 0, stream>>>(
            lnb, ff1_wb + (size_t)l * DFFN * DD, ff1_b + l * DFFN, ffb, NN, DFFN, DD);
        if (l == 0) {
            mgemm_ln_kernel<false><<<256, 512, 0, stream>>>(
                ffb, ff2_wb, ff2_b, hA,
                ln2_w, ln2_b, hB, hBb,
                nullptr, nullptr, nullptr, NN, DFFN);
        } else {
            mgemm_ln_kernel<true><<<256, 512, 0, stream>>>(
                ffb, ff2_wb + (size_t)DD * DFFN, ff2_b + DD, hA,
                ln2_w + DD, ln2_b + DD, nullptr, nullptr,
                pred_w, pred_b, outp, NN, DFFN);
        }
    }
}

// Round 4
// 378.686 us; speedup vs baseline: 1.0220x; 1.0061x over previous
//
#include <hip/hip_runtime.h>
#include <hip/hip_bf16.h>

#define NN 8192
#define EE 262144
#define BB 8
#define LL 1024
#define HH 8
#define DD 256
#define DFFN 2048

typedef short s8v __attribute__((ext_vector_type(8)));
typedef float f32x4 __attribute__((ext_vector_type(4)));
typedef unsigned short ushort;

__device__ inline ushort f2bf(float f) {
    unsigned u = __float_as_uint(f);
    u = (u + 0x7fffu + ((u >> 16) & 1u)) >> 16;
    return (ushort)u;
}
__device__ inline float bf2f(ushort u) {
    return __uint_as_float(((unsigned)u) << 16);
}

// ---------------------------------------------------------------------------
// ff1 GEMM: 128x128 tile, BK=64, double-buffered LDS with counted-vmcnt
// 2-phase prefetch. bias+relu+bf16 out. Grid (M/128,N/128). 64 KB LDS.
// ---------------------------------------------------------------------------
__global__ __launch_bounds__(256) void mgemm_ff1_kernel(
    const ushort* __restrict__ A, const ushort* __restrict__ W,
    const float* __restrict__ bias, ushort* __restrict__ Cb,
    int M, int N, int K)
{
    __shared__ ushort As[2][128 * 64];
    __shared__ ushort Bs[2][128 * 64];
    int t = threadIdx.x;
    int l = t & 63;
    int quad = l >> 4, l15 = l & 15;
    int r7 = l15 & 7;
    int w = t >> 6;
    int wm = (w >> 1) * 64, wn = (w & 1) * 64;
    int m0 = blockIdx.x * 128, n0 = blockIdx.y * 128;

    int goffA[4], goffB[4], lo[4];
#pragma unroll
    for (int i = 0; i < 4; ++i) {
        int chunk = i * 256 + t;
        int r = chunk >> 3, p = chunk & 7;
        int qs = (p ^ (r & 7)) * 8;
        goffA[i] = (m0 + r) * K + qs;
        goffB[i] = (n0 + r) * K + qs;
        lo[i] = chunk * 8;
    }

#define STAGE_F(k0, bf)                                                         \
    {                                                                           \
        _Pragma("unroll")                                                       \
        for (int i = 0; i < 4; ++i) {                                           \
            __builtin_amdgcn_global_load_lds(                                   \
                (const __attribute__((address_space(1))) unsigned int*)         \
                    (A + goffA[i] + (k0)),                                      \
                (__attribute__((address_space(3))) unsigned int*)(&As[bf][0] + lo[i]), 16, 0, 0); \
            __builtin_amdgcn_global_load_lds(                                   \
                (const __attribute__((address_space(1))) unsigned int*)         \
                    (W + goffB[i] + (k0)),                                      \
                (__attribute__((address_space(3))) unsigned int*)(&Bs[bf][0] + lo[i]), 16, 0, 0); \
        }                                                                       \
    }

    f32x4 z = {0.f, 0.f, 0.f, 0.f};
    f32x4 acc[4][4];
#pragma unroll
    for (int i = 0; i < 4; ++i)
#pragma unroll
        for (int j = 0; j < 4; ++j) acc[i][j] = z;

    int nt = K >> 6;
    STAGE_F(0, 0);
    for (int ks = 0; ks < nt; ++ks) {
        int cur = ks & 1;
        if (ks + 1 < nt) {
            STAGE_F((ks + 1) << 6, cur ^ 1);
            asm volatile("s_waitcnt vmcnt(8)" ::: "memory");
        } else {
            asm volatile("s_waitcnt vmcnt(0)" ::: "memory");
        }
        __builtin_amdgcn_s_barrier();
        __builtin_amdgcn_sched_barrier(0);
#pragma unroll
        for (int kk = 0; kk < 2; ++kk) {
            int off = ((kk * 4 + quad) ^ r7) * 8;
            s8v af[4], bfv[4];
#pragma unroll
            for (int i = 0; i < 4; ++i) {
                af[i]  = *(const s8v*)(&As[cur][0] + (wm + i * 16 + l15) * 64 + off);
                bfv[i] = *(const s8v*)(&Bs[cur][0] + (wn + i * 16 + l15) * 64 + off);
            }
#pragma unroll
            for (int mi = 0; mi < 4; ++mi)
#pragma unroll
                for (int ni = 0; ni < 4; ++ni)
                    acc[mi][ni] = __builtin_amdgcn_mfma_f32_16x16x32_bf16(
                        af[mi], bfv[ni], acc[mi][ni], 0, 0, 0);
        }
        __builtin_amdgcn_sched_barrier(0);
        __builtin_amdgcn_s_barrier();
    }
#undef STAGE_F

#pragma unroll
    for (int mi = 0; mi < 4; ++mi) {
#pragma unroll
        for (int ni = 0; ni < 4; ++ni) {
            int n = n0 + wn + ni * 16 + l15;
            float bi = bias[n];
#pragma unroll
            for (int r = 0; r < 4; ++r) {
                int m = m0 + wm + mi * 16 + quad * 4 + r;
                float v = fmaxf(acc[mi][ni][r] + bi, 0.f);
                Cb[(size_t)m * N + n] = f2bf(v);
            }
        }
    }
}

// ---------------------------------------------------------------------------
// 64x64-tile, BK=64, mod-8 XOR swizzle. ASD: fused GAT logits.
// ---------------------------------------------------------------------------
template<bool ASD>
__global__ __launch_bounds__(256) void mgemm64_kernel(
    const ushort* __restrict__ A, const ushort* __restrict__ W,
    ushort* __restrict__ Cb,
    const float* __restrict__ atts, const float* __restrict__ attd,
    float* __restrict__ a_s, float* __restrict__ a_d, int M, int N, int K)
{
    __shared__ ushort As[64 * 64];
    __shared__ ushort Bs[64 * 64];
    int t = threadIdx.x;
    int l = t & 63;
    int quad = l >> 4, l15 = l & 15;
    int r7 = l15 & 7;
    int w = t >> 6;
    int wm = (w >> 1) * 32, wn = (w & 1) * 32;
    int m0 = blockIdx.x * 64, n0 = blockIdx.y * 64;

    f32x4 z = {0.f, 0.f, 0.f, 0.f};
    f32x4 acc[2][2];
#pragma unroll
    for (int i = 0; i < 2; ++i)
#pragma unroll
        for (int j = 0; j < 2; ++j) acc[i][j] = z;

    for (int k0 = 0; k0 < K; k0 += 64) {
#pragma unroll
        for (int i = 0; i < 2; ++i) {
            int chunk = i * 256 + t;
            int r = chunk >> 3, p = chunk & 7;
            int qs = (p ^ (r & 7)) * 8;
            __builtin_amdgcn_global_load_lds(
                (const __attribute__((address_space(1))) unsigned int*)
                    (A + (size_t)(m0 + r) * K + k0 + qs),
                (__attribute__((address_space(3))) unsigned int*)(As + chunk * 8), 16, 0, 0);
            __builtin_amdgcn_global_load_lds(
                (const __attribute__((address_space(1))) unsigned int*)
                    (W + (size_t)(n0 + r) * K + k0 + qs),
                (__attribute__((address_space(3))) unsigned int*)(Bs + chunk * 8), 16, 0, 0);
        }
        __syncthreads();
#pragma unroll
        for (int kk = 0; kk < 2; ++kk) {
            s8v af[2], bfv[2];
            int off = ((kk * 4 + quad) ^ r7) * 8;
#pragma unroll
            for (int i = 0; i < 2; ++i) {
                af[i]  = *(const s8v*)(As + (wm + i * 16 + l15) * 64 + off);
                bfv[i] = *(const s8v*)(Bs + (wn + i * 16 + l15) * 64 + off);
            }
#pragma unroll
            for (int mi = 0; mi < 2; ++mi)
#pragma unroll
                for (int ni = 0; ni < 2; ++ni)
                    acc[mi][ni] = __builtin_amdgcn_mfma_f32_16x16x32_bf16(
                        af[mi], bfv[ni], acc[mi][ni], 0, 0, 0);
        }
        __syncthreads();
    }

#pragma unroll
    for (int mi = 0; mi < 2; ++mi) {
#pragma unroll
        for (int ni = 0; ni < 2; ++ni) {
            int n = n0 + wn + ni * 16 + l15;
#pragma unroll
            for (int r = 0; r < 4; ++r) {
                int m = m0 + wm + mi * 16 + quad * 4 + r;
                Cb[(size_t)m * N + n] = f2bf(acc[mi][ni][r]);
            }
        }
    }

    if (ASD) {
        int head = ((n0 + wn) >> 5) & 7;
        float as0 = atts[head * 32 + l15];
        float as1 = atts[head * 32 + 16 + l15];
        float ad0 = attd[head * 32 + l15];
        float ad1 = attd[head * 32 + 16 + l15];
#pragma unroll
        for (int mi = 0; mi < 2; ++mi)
#pragma unroll
            for (int r = 0; r < 4; ++r) {
                float sp = acc[mi][0][r] * as0 + acc[mi][1][r] * as1;
                float dp = acc[mi][0][r] * ad0 + acc[mi][1][r] * ad1;
#pragma unroll
                for (int off = 1; off < 16; off <<= 1) {
                    sp += __shfl_xor(sp, off);
                    dp += __shfl_xor(dp, off);
                }
                if (l15 == 0) {
                    int m = m0 + wm + mi * 16 + quad * 4 + r;
                    a_s[m * 8 + head] = sp;
                    a_d[m * 8 + head] = dp;
                }
            }
    }
}

// ---------------------------------------------------------------------------
// Fused GAT-L0 GEMM (+ASD logits) AND padded-CSR scatter in one dispatch.
// ---------------------------------------------------------------------------
__global__ __launch_bounds__(256) void gemm0_scatter_kernel(
    const ushort* __restrict__ A, const ushort* __restrict__ W,
    ushort* __restrict__ Cb,
    const float* __restrict__ atts, const float* __restrict__ attd,
    float* __restrict__ a_s, float* __restrict__ a_d,
    const int* __restrict__ ei, int* __restrict__ deg, int* __restrict__ col)
{
    __shared__ ushort As[64 * 64];
    __shared__ ushort Bs[64 * 64];
    int t = threadIdx.x;

    if (blockIdx.x >= 512) {
        int e = (blockIdx.x - 512) * 256 + t;
        if (e < EE + NN) {
            int s, d;
            if (e < EE) { s = ei[e]; d = ei[EE + e]; } else { s = e - EE; d = s; }
            int slot = atomicAdd(&deg[d], 1);
            col[(d << 7) + slot] = s;
        }
        return;
    }

    int l = t & 63;
    int quad = l >> 4, l15 = l & 15;
    int r7 = l15 & 7;
    int w = t >> 6;
    int wm = (w >> 1) * 32, wn = (w & 1) * 32;
    int m0 = (blockIdx.x & 127) * 64, n0 = (blockIdx.x >> 7) * 64;
    const int K = 64;

    f32x4 z = {0.f, 0.f, 0.f, 0.f};
    f32x4 acc[2][2];
#pragma unroll
    for (int i = 0; i < 2; ++i)
#pragma unroll
        for (int j = 0; j < 2; ++j) acc[i][j] = z;

#pragma unroll
    for (int i = 0; i < 2; ++i) {
        int chunk = i * 256 + t;
        int r = chunk >> 3, p = chunk & 7;
        int qs = (p ^ (r & 7)) * 8;
        __builtin_amdgcn_global_load_lds(
            (const __attribute__((address_space(1))) unsigned int*)
                (A + (size_t)(m0 + r) * K + qs),
            (__attribute__((address_space(3))) unsigned int*)(As + chunk * 8), 16, 0, 0);
        __builtin_amdgcn_global_load_lds(
            (const __attribute__((address_space(1))) unsigned int*)
                (W + (size_t)(n0 + r) * K + qs),
            (__attribute__((address_space(3))) unsigned int*)(Bs + chunk * 8), 16, 0, 0);
    }
    __syncthreads();
#pragma unroll
    for (int kk = 0; kk < 2; ++kk) {
        s8v af[2], bfv[2];
        int off = ((kk * 4 + quad) ^ r7) * 8;
#pragma unroll
        for (int i = 0; i < 2; ++i) {
            af[i]  = *(const s8v*)(As + (wm + i * 16 + l15) * 64 + off);
            bfv[i] = *(const s8v*)(Bs + (wn + i * 16 + l15) * 64 + off);
        }
#pragma unroll
        for (int mi = 0; mi < 2; ++mi)
#pragma unroll
            for (int ni = 0; ni < 2; ++ni)
                acc[mi][ni] = __builtin_amdgcn_mfma_f32_16x16x32_bf16(
                    af[mi], bfv[ni], acc[mi][ni], 0, 0, 0);
    }

#pragma unroll
    for (int mi = 0; mi < 2; ++mi) {
#pragma unroll
        for (int ni = 0; ni < 2; ++ni) {
            int n = n0 + wn + ni * 16 + l15;
#pragma unroll
            for (int r = 0; r < 4; ++r) {
                int m = m0 + wm + mi * 16 + quad * 4 + r;
                Cb[(size_t)m * DD + n] = f2bf(acc[mi][ni][r]);
            }
        }
    }

    {
        int head = ((n0 + wn) >> 5) & 7;
        float as0 = atts[head * 32 + l15];
        float as1 = atts[head * 32 + 16 + l15];
        float ad0 = attd[head * 32 + l15];
        float ad1 = attd[head * 32 + 16 + l15];
#pragma unroll
        for (int mi = 0; mi < 2; ++mi)
#pragma unroll
            for (int r = 0; r < 4; ++r) {
                float sp = acc[mi][0][r] * as0 + acc[mi][1][r] * as1;
                float dp = acc[mi][0][r] * ad0 + acc[mi][1][r] * ad1;
#pragma unroll
                for (int off = 1; off < 16; off <<= 1) {
                    sp += __shfl_xor(sp, off);
                    dp += __shfl_xor(dp, off);
                }
                if (l15 == 0) {
                    int m = m0 + wm + mi * 16 + quad * 4 + r;
                    a_s[m * 8 + head] = sp;
                    a_d[m * 8 + head] = dp;
                }
            }
    }
}

// ---------------------------------------------------------------------------
// Fused GEMM + bias + residual + LayerNorm (+ optional pred head).
// v4: exact per-wave vmcnt counts (waves 0-3 issue 5 loads/tile, waves 4-7
// issue 4) — uniform vmcnt(4) forced waves 0-3 to eat a full load latency
// every K-step (32 steps at K=2048).
// ---------------------------------------------------------------------------
template<bool PRED>
__global__ __launch_bounds__(512) void mgemm_ln_kernel(
    const ushort* __restrict__ A, const ushort* __restrict__ W,
    const float* __restrict__ bias, const float* __restrict__ res,
    const float* __restrict__ lnw, const float* __restrict__ lnbb,
    float* __restrict__ Xf, ushort* __restrict__ Xb,
    const float* __restrict__ pw, const float* __restrict__ pb,
    float* __restrict__ pout, int M, int K)
{
    __shared__ ushort As[2][32 * 64];
    __shared__ ushort Bs[2][256 * 64];
    __shared__ float red[2][4][32];
    __shared__ float predred[4][32][3];

    int t = threadIdx.x;
    int l = t & 63;
    int quad = l >> 4, l15 = l & 15;
    int r7 = l15 & 7;
    int w = t >> 6;            // 0..7
    int mh = w >> 2;           // row half 0/1 (16 rows each)
    int cw = w & 3;            // col wave 0..3
    int n0w = cw * 64;
    int m0 = blockIdx.x * 32;

    int goffB[4], loB[4];
#pragma unroll
    for (int i = 0; i < 4; ++i) {
        int chunk = i * 512 + t;
        int r = chunk >> 3, p = chunk & 7;
        goffB[i] = r * K + (p ^ (r & 7)) * 8;
        loB[i] = chunk * 8;
    }
    int rA = t >> 3, pA = t & 7;
    int goffA = (m0 + rA) * K + (pA ^ (rA & 7)) * 8;
    int loA = t * 8;

#define STAGE_LN(k0, bf)                                                        \
    {                                                                           \
        _Pragma("unroll")                                                       \
        for (int i = 0; i < 4; ++i)                                             \
            __builtin_amdgcn_global_load_lds(                                   \
                (const __attribute__((address_space(1))) unsigned int*)         \
                    (W + goffB[i] + (k0)),                                      \
                (__attribute__((address_space(3))) unsigned int*)(&Bs[bf][0] + loB[i]), 16, 0, 0); \
        if (t < 256)                                                            \
            __builtin_amdgcn_global_load_lds(                                   \
                (const __attribute__((address_space(1))) unsigned int*)         \
                    (A + goffA + (k0)),                                         \
                (__attribute__((address_space(3))) unsigned int*)(&As[bf][0] + loA), 16, 0, 0); \
    }

    f32x4 z = {0.f, 0.f, 0.f, 0.f};
    f32x4 acc[4];
#pragma unroll
    for (int i = 0; i < 4; ++i) acc[i] = z;

    int nt = K >> 6;
    STAGE_LN(0, 0);
    for (int ks = 0; ks < nt; ++ks) {
        int cur = ks & 1;
        if (ks + 1 < nt) {
            STAGE_LN((ks + 1) << 6, cur ^ 1);
            if (w < 4) { asm volatile("s_waitcnt vmcnt(5)" ::: "memory"); }
            else       { asm volatile("s_waitcnt vmcnt(4)" ::: "memory"); }
        } else {
            asm volatile("s_waitcnt vmcnt(0)" ::: "memory");
        }
        __builtin_amdgcn_s_barrier();
        __builtin_amdgcn_sched_barrier(0);
#pragma unroll
        for (int kk = 0; kk < 2; ++kk) {
            int off = ((kk * 4 + quad) ^ r7) * 8;
            s8v af = *(const s8v*)(&As[cur][0] + (mh * 16 + l15) * 64 + off);
#pragma unroll
            for (int ni = 0; ni < 4; ++ni) {
                s8v bfv = *(const s8v*)(&Bs[cur][0] + (n0w + ni * 16 + l15) * 64 + off);
                acc[ni] = __builtin_amdgcn_mfma_f32_16x16x32_bf16(af, bfv, acc[ni], 0, 0, 0);
            }
        }
        __builtin_amdgcn_sched_barrier(0);
        __builtin_amdgcn_s_barrier();
    }
#undef STAGE_LN

    float v[4][4];
#pragma unroll
    for (int ni = 0; ni < 4; ++ni) {
        int n = n0w + ni * 16 + l15;
        float bi = bias[n];
#pragma unroll
        for (int r = 0; r < 4; ++r) {
            int m = m0 + mh * 16 + quad * 4 + r;
            v[ni][r] = acc[ni][r] + bi + res[(size_t)m * DD + n];
        }
    }
    float s1[4], s2[4];
#pragma unroll
    for (int r = 0; r < 4; ++r) {
        s1[r] = 0.f; s2[r] = 0.f;
#pragma unroll
        for (int ni = 0; ni < 4; ++ni) { s1[r] += v[ni][r]; s2[r] += v[ni][r] * v[ni][r]; }
#pragma unroll
        for (int off = 1; off < 16; off <<= 1) {
            s1[r] += __shfl_xor(s1[r], off);
            s2[r] += __shfl_xor(s2[r], off);
        }
    }
    if (l15 == 0)
#pragma unroll
        for (int r = 0; r < 4; ++r) {
            int row = mh * 16 + quad * 4 + r;
            red[0][cw][row] = s1[r];
            red[1][cw][row] = s2[r];
        }
    __syncthreads();
    float mu[4], rstd[4];
#pragma unroll
    for (int r = 0; r < 4; ++r) {
        int row = mh * 16 + quad * 4 + r;
        float S1 = red[0][0][row] + red[0][1][row] + red[0][2][row] + red[0][3][row];
        float S2 = red[1][0][row] + red[1][1][row] + red[1][2][row] + red[1][3][row];
        mu[r] = S1 * (1.f / 256.f);
        float var = S2 * (1.f / 256.f) - mu[r] * mu[r];
        rstd[r] = rsqrtf(fmaxf(var, 0.f) + 1e-5f);
    }

    float ov[4][4];
#pragma unroll
    for (int ni = 0; ni < 4; ++ni) {
        int n = n0w + ni * 16 + l15;
        float wl = lnw[n], bl = lnbb[n];
#pragma unroll
        for (int r = 0; r < 4; ++r)
            ov[ni][r] = (v[ni][r] - mu[r]) * rstd[r] * wl + bl;
    }

    if (PRED) {
        float ps[3][4] = {};
#pragma unroll
        for (int ni = 0; ni < 4; ++ni) {
            int n = n0w + ni * 16 + l15;
            float w0 = pw[n], w1 = pw[DD + n], w2 = pw[2 * DD + n];
#pragma unroll
            for (int r = 0; r < 4; ++r) {
                ps[0][r] += ov[ni][r] * w0;
                ps[1][r] += ov[ni][r] * w1;
                ps[2][r] += ov[ni][r] * w2;
            }
        }
#pragma unroll
        for (int o3 = 0; o3 < 3; ++o3)
#pragma unroll
            for (int r = 0; r < 4; ++r)
#pragma unroll
                for (int off = 1; off < 16; off <<= 1)
                    ps[o3][r] += __shfl_xor(ps[o3][r], off);
        if (l15 == 0)
#pragma unroll
            for (int o3 = 0; o3 < 3; ++o3)
#pragma unroll
                for (int r = 0; r < 4; ++r)
                    predred[cw][mh * 16 + quad * 4 + r][o3] = ps[o3][r];
        __syncthreads();
        if (t < 96) {
            int row = t / 3, o3 = t % 3;
            float s = predred[0][row][o3] + predred[1][row][o3]
                    + predred[2][row][o3] + predred[3][row][o3] + pb[o3];
            pout[(size_t)(m0 + row) * 3 + o3] = s;
        }
    } else {
#pragma unroll
        for (int ni = 0; ni < 4; ++ni) {
            int n = n0w + ni * 16 + l15;
#pragma unroll
            for (int r = 0; r < 4; ++r) {
                int m = m0 + mh * 16 + quad * 4 + r;
                Xf[(size_t)m * DD + n] = ov[ni][r];
                Xb[(size_t)m * DD + n] = f2bf(ov[ni][r]);
            }
        }
    }
}

// ---------------------------------------------------------------------------
// qkv GEMM, 64x64 tile BK=64 (grid 128x12), fused re-layout epilogue.
// v2: V-section stores routed through an LDS transpose -> coalesced 16B
// stores along ll2 (the old direct Vt store hit ~16 cache lines per wave-op).
// ---------------------------------------------------------------------------
__global__ __launch_bounds__(256) void mgemm_qkv_kernel(
    const ushort* __restrict__ A, const ushort* __restrict__ W,
    const float* __restrict__ bias,
    ushort* __restrict__ Qb, ushort* __restrict__ Kb, ushort* __restrict__ Vt,
    int M, int K)
{
    __shared__ ushort As[64 * 64];
    __shared__ ushort Bs[64 * 64];
    __shared__ ushort Vts[64][72];
    int t = threadIdx.x;
    int l = t & 63;
    int quad = l >> 4, l15 = l & 15;
    int r7 = l15 & 7;
    int w = t >> 6;
    int wm = (w >> 1) * 32, wn = (w & 1) * 32;
    int m0 = blockIdx.x * 64, n0 = blockIdx.y * 64;

    f32x4 z = {0.f, 0.f, 0.f, 0.f};
    f32x4 acc[2][2];
#pragma unroll
    for (int i = 0; i < 2; ++i)
#pragma unroll
        for (int j = 0; j < 2; ++j) acc[i][j] = z;

    for (int k0 = 0; k0 < K; k0 += 64) {
#pragma unroll
        for (int i = 0; i < 2; ++i) {
            int chunk = i * 256 + t;
            int r = chunk >> 3, p = chunk & 7;
            int qs = (p ^ (r & 7)) * 8;
            __builtin_amdgcn_global_load_lds(
                (const __attribute__((address_space(1))) unsigned int*)
                    (A + (size_t)(m0 + r) * K + k0 + qs),
                (__attribute__((address_space(3))) unsigned int*)(As + chunk * 8), 16, 0, 0);
            __builtin_amdgcn_global_load_lds(
                (const __attribute__((address_space(1))) unsigned int*)
                    (W + (size_t)(n0 + r) * K + k0 + qs),
                (__attribute__((address_space(3))) unsigned int*)(Bs + chunk * 8), 16, 0, 0);
        }
        __syncthreads();
#pragma unroll
        for (int kk = 0; kk < 2; ++kk) {
            s8v af[2], bfv[2];
            int off = ((kk * 4 + quad) ^ r7) * 8;
#pragma unroll
            for (int i = 0; i < 2; ++i) {
                af[i]  = *(const s8v*)(As + (wm + i * 16 + l15) * 64 + off);
                bfv[i] = *(const s8v*)(Bs + (wn + i * 16 + l15) * 64 + off);
            }
#pragma unroll
            for (int mi = 0; mi < 2; ++mi)
#pragma unroll
                for (int ni = 0; ni < 2; ++ni)
                    acc[mi][ni] = __builtin_amdgcn_mfma_f32_16x16x32_bf16(
                        af[mi], bfv[ni], acc[mi][ni], 0, 0, 0);
        }
        __syncthreads();
    }

    int sec = n0 >> 8;   // block-uniform: section 0=Q, 1=K, 2=V
    if (sec < 2) {
#pragma unroll
        for (int mi = 0; mi < 2; ++mi) {
#pragma unroll
            for (int ni = 0; ni < 2; ++ni) {
                int n = n0 + wn + ni * 16 + l15;
                int hc = n & 255;
                int hh = hc >> 5, c = hc & 31;
                float bv = bias[n];
#pragma unroll
                for (int r = 0; r < 4; ++r) {
                    int m = m0 + wm + mi * 16 + quad * 4 + r;
                    float v = acc[mi][ni][r] + bv;
                    int b = m >> 10, ll2 = m & 1023;
                    int bh = b * 8 + hh;
                    if (sec == 0)
                        Qb[(size_t)bh * 32768 + ll2 * 32 + c] = f2bf(v * 0.17677669529663687f);
                    else
                        Kb[(size_t)bh * 32768 + ll2 * 32 + c] = f2bf(v);
                }
            }
        }
    } else {
        // V: transpose 64x64 tile in LDS, then coalesced 16B stores along ll2.
#pragma unroll
        for (int mi = 0; mi < 2; ++mi) {
#pragma unroll
            for (int ni = 0; ni < 2; ++ni) {
                int nl = wn + ni * 16 + l15;
                float bv = bias[n0 + nl];
#pragma unroll
                for (int r = 0; r < 4; ++r) {
                    int ml = wm + mi * 16 + quad * 4 + r;
                    Vts[nl][ml] = f2bf(acc[mi][ni][r] + bv);
                }
            }
        }
        __syncthreads();
        int b = m0 >> 10;
        int ll2base = m0 & 1023;
#pragma unroll
        for (int it = 0; it < 2; ++it) {
            int chunk = it * 256 + t;
            int nl = chunk >> 3;
            int me = (chunk & 7) * 8;
            int n = n0 + nl;
            int hh = (n & 255) >> 5, c = n & 31;
            ushort* dst = Vt + (size_t)(b * 8 + hh) * 32768 + (size_t)c * 1024 + ll2base + me;
            *(s8v*)dst = *(const s8v*)&Vts[nl][me];
        }
    }
}

// ---------------------------------------------------------------------------
// Merged cast kernel: all weights + x fp32->bf16, plus deg zeroing.
// ---------------------------------------------------------------------------
__global__ __launch_bounds__(256) void castall_kernel(
    const float* __restrict__ W0, const float* __restrict__ W12,
    const float* __restrict__ qkvw, const float* __restrict__ outw,
    const float* __restrict__ f1w, const float* __restrict__ f2w,
    const float* __restrict__ x,
    ushort* __restrict__ W0b, ushort* __restrict__ W12b,
    ushort* __restrict__ qkvb, ushort* __restrict__ outb,
    ushort* __restrict__ f1b, ushort* __restrict__ f2b,
    ushort* __restrict__ xb, int* __restrict__ deg)
{
    int tid = blockIdx.x * 256 + threadIdx.x;
    if (tid < 2048) *(int4*)(deg + tid * 4) = make_int4(0, 0, 0, 0);
    int e = tid * 4;
    if (e >= 3293184) return;
    const float* s; ushort* d; int off;
    if (e < 16384)        { s = W0;   d = W0b;  off = e; }
    else if (e < 147456)  { s = W12;  d = W12b; off = e - 16384; }
    else if (e < 540672)  { s = qkvw; d = qkvb; off = e - 147456; }
    else if (e < 671744)  { s = outw; d = outb; off = e - 540672; }
    else if (e < 1720320) { s = f1w;  d = f1b;  off = e - 671744; }
    else if (e < 2768896) { s = f2w;  d = f2b;  off = e - 1720320; }
    else                  { s = x;    d = xb;   off = e - 2768896; }
    float4 v = *(const float4*)(s + off);
    d[off + 0] = f2bf(v.x); d[off + 1] = f2bf(v.y);
    d[off + 2] = f2bf(v.z); d[off + 3] = f2bf(v.w);
}

// ---------------------------------------------------------------------------
// GAT aggregation: SINGLE pass over edges.
// ---------------------------------------------------------------------------
template<bool WF>
__global__ __launch_bounds__(256) void gat_agg_kernel(
    const ushort* __restrict__ hlinb, const float* __restrict__ a_s,
    const float* __restrict__ a_d, const int* __restrict__ deg,
    const int* __restrict__ col, const float* __restrict__ bias,
    float* __restrict__ out, ushort* __restrict__ outb)
{
    int wid = threadIdx.x >> 6, lane = threadIdx.x & 63;
    int dst = blockIdx.x * 4 + wid;
    int start = dst << 7;
    int end = start + deg[dst];
    int myh = lane >> 3;
    float adh = a_d[(size_t)dst * HH + myh];

    float a0 = 0.f, a1 = 0.f, a2 = 0.f, a3 = 0.f, den = 0.f;
    int e = start;
    for (; e + 4 <= end; e += 4) {
        int s0 = col[e], s1 = col[e + 1], s2 = col[e + 2], s3 = col[e + 3];
        float v0 = a_s[(size_t)s0 * HH + myh] + adh;
        float v1 = a_s[(size_t)s1 * HH + myh] + adh;
        float v2 = a_s[(size_t)s2 * HH + myh] + adh;
        float v3 = a_s[(size_t)s3 * HH + myh] + adh;
        v0 = v0 > 0.f ? v0 : 0.2f * v0;
        v1 = v1 > 0.f ? v1 : 0.2f * v1;
        v2 = v2 > 0.f ? v2 : 0.2f * v2;
        v3 = v3 > 0.f ? v3 : 0.2f * v3;
        float p0 = __expf(v0), p1 = __expf(v1), p2 = __expf(v2), p3 = __expf(v3);
        den += p0 + p1 + p2 + p3;
        uint2 h0 = *(const uint2*)(hlinb + (size_t)s0 * DD + lane * 4);
        uint2 h1 = *(const uint2*)(hlinb + (size_t)s1 * DD + lane * 4);
        uint2 h2 = *(const uint2*)(hlinb + (size_t)s2 * DD + lane * 4);
        uint2 h3 = *(const uint2*)(hlinb + (size_t)s3 * DD + lane * 4);
        a0 += p0 * bf2f((ushort)(h0.x & 0xffff)) + p1 * bf2f((ushort)(h1.x & 0xffff))
            + p2 * bf2f((ushort)(h2.x & 0xffff)) + p3 * bf2f((ushort)(h3.x & 0xffff));
        a1 += p0 * bf2f((ushort)(h0.x >> 16)) + p1 * bf2f((ushort)(h1.x >> 16))
            + p2 * bf2f((ushort)(h2.x >> 16)) + p3 * bf2f((ushort)(h3.x >> 16));
        a2 += p0 * bf2f((ushort)(h0.y & 0xffff)) + p1 * bf2f((ushort)(h1.y & 0xffff))
            + p2 * bf2f((ushort)(h2.y & 0xffff)) + p3 * bf2f((ushort)(h3.y & 0xffff));
        a3 += p0 * bf2f((ushort)(h0.y >> 16)) + p1 * bf2f((ushort)(h1.y >> 16))
            + p2 * bf2f((ushort)(h2.y >> 16)) + p3 * bf2f((ushort)(h3.y >> 16));
    }
    for (; e < end; ++e) {
        int s = col[e];
        float v = a_s[(size_t)s * HH + myh] + adh;
        v = v > 0.f ? v : 0.2f * v;
        float p = __expf(v);
        den += p;
        uint2 hv = *(const uint2*)(hlinb + (size_t)s * DD + lane * 4);
        a0 += p * bf2f((ushort)(hv.x & 0xffff));
        a1 += p * bf2f((ushort)(hv.x >> 16));
        a2 += p * bf2f((ushort)(hv.y & 0xffff));
        a3 += p * bf2f((ushort)(hv.y >> 16));
    }
    float inv = 1.f / den;
    float4 bv = *(const float4*)(bias + lane * 4);
    float r0 = fmaxf(a0 * inv + bv.x, 0.f);
    float r1 = fmaxf(a1 * inv + bv.y, 0.f);
    float r2 = fmaxf(a2 * inv + bv.z, 0.f);
    float r3 = fmaxf(a3 * inv + bv.w, 0.f);
    if (WF) {
        float* op = out + (size_t)dst * DD + lane * 4;
        op[0] = r0; op[1] = r1; op[2] = r2; op[3] = r3;
    }
    ushort* ob = outb + (size_t)dst * DD + lane * 4;
    ob[0] = f2bf(r0); ob[1] = f2bf(r1); ob[2] = f2bf(r2); ob[3] = f2bf(r3);
}

// ---------------------------------------------------------------------------
// Flash-style MFMA attention (denominator on the MFMA pipe via P*1).
// ---------------------------------------------------------------------------
__global__ __launch_bounds__(256, 2) void attn_flash_kernel(
    const ushort* __restrict__ Qb, const ushort* __restrict__ Kb,
    const ushort* __restrict__ Vt, ushort* __restrict__ outb)
{
    __shared__ ushort Ks[2][128 * 32];
    __shared__ ushort Vs[2][32 * 128];
    __shared__ ushort pw[4][32][132];

    int t = threadIdx.x;
    int w = t >> 6, lane = t & 63;
    int quad = lane >> 4, l15 = lane & 15;
    int kq = (quad ^ ((l15 >> 1) & 3)) * 8;
    int bh = blockIdx.y;
    int q0 = blockIdx.x * 128 + w * 32;
    int b = bh >> 3, h = bh & 7;

    const ushort* qbase = Qb + (size_t)bh * 32768;
    const ushort* kbase = Kb + (size_t)bh * 32768;
    const ushort* vbase = Vt + (size_t)bh * 32768;

    s8v aq0 = *(const s8v*)(qbase + (q0 + l15) * 32 + quad * 8);
    s8v aq1 = *(const s8v*)(qbase + (q0 + 16 + l15) * 32 + quad * 8);

    s8v vone;
#pragma unroll
    for (int i = 0; i < 8; ++i) vone[i] = (short)0x3F80;  // bf16 1.0

    int i0 = t, i1 = 256 + t;
    int kr0 = i0 >> 2, kcs0 = (((i0 & 3)) ^ ((kr0 >> 1) & 3)) * 8;
    int kr1 = i1 >> 2, kcs1 = (((i1 & 3)) ^ ((kr1 >> 1) & 3)) * 8;
    int vr0 = i0 >> 4, vcs0 = ((i0 & 15) ^ (vr0 & 15)) * 8;
    int vr1 = i1 >> 4, vcs1 = ((i1 & 15) ^ (vr1 & 15)) * 8;

#define STAGE(ch, bf)                                                          \
    {                                                                          \
        int j0 = (ch) * 128;                                                   \
        __builtin_amdgcn_global_load_lds(                                      \
            (const __attribute__((address_space(1))) unsigned int*)            \
                (kbase + (size_t)(j0 + kr0) * 32 + kcs0),                      \
            (__attribute__((address_space(3))) unsigned int*)(Ks[bf] + i0 * 8), 16, 0, 0); \
        __builtin_amdgcn_global_load_lds(                                      \
            (const __attribute__((address_space(1))) unsigned int*)            \
                (kbase + (size_t)(j0 + kr1) * 32 + kcs1),                      \
            (__attribute__((address_space(3))) unsigned int*)(Ks[bf] + i1 * 8), 16, 0, 0); \
        __builtin_amdgcn_global_load_lds(                                      \
            (const __attribute__((address_space(1))) unsigned int*)            \
                (vbase + (size_t)vr0 * 1024 + j0 + vcs0),                      \
            (__attribute__((address_space(3))) unsigned int*)(Vs[bf] + i0 * 8), 16, 0, 0); \
        __builtin_amdgcn_global_load_lds(                                      \
            (const __attribute__((address_space(1))) unsigned int*)            \
                (vbase + (size_t)vr1 * 1024 + j0 + vcs1),                      \
            (__attribute__((address_space(3))) unsigned int*)(Vs[bf] + i1 * 8), 16, 0, 0); \
    }

    f32x4 z = {0.f, 0.f, 0.f, 0.f};
    f32x4 o00 = z, o01 = z, o10 = z, o11 = z;
    f32x4 od0 = z, od1 = z;

    STAGE(0, 0);
    for (int ch = 0; ch < 8; ++ch) {
        int bf = ch & 1;
        __syncthreads();
        if (ch < 7) STAGE(ch + 1, bf ^ 1);

        f32x4 s0[8], s1[8];
#pragma unroll
        for (int kk = 0; kk < 8; ++kk) {
            s8v bk = *(const s8v*)(Ks[bf] + (kk * 16 + l15) * 32 + kq);
            s0[kk] = __builtin_amdgcn_mfma_f32_16x16x32_bf16(aq0, bk, z, 0, 0, 0);
            s1[kk] = __builtin_amdgcn_mfma_f32_16x16x32_bf16(aq1, bk, z, 0, 0, 0);
        }

#pragma unroll
        for (int kk = 0; kk < 8; ++kk) {
#pragma unroll
            for (int r = 0; r < 4; ++r) {
                float p0 = __expf(s0[kk][r]);
                float p1 = __expf(s1[kk][r]);
                pw[w][quad * 4 + r][kk * 16 + l15]      = f2bf(p0);
                pw[w][16 + quad * 4 + r][kk * 16 + l15] = f2bf(p1);
            }
        }

#pragma unroll
        for (int kk = 0; kk < 4; ++kk) {
            s8v ap0 = *(const s8v*)(&pw[w][l15][kk * 32 + quad * 8]);
            s8v ap1 = *(const s8v*)(&pw[w][16 + l15][kk * 32 + quad * 8]);
            int c0 = ((kk * 4 + quad) ^ l15) * 8;
            s8v b0 = *(const s8v*)(Vs[bf] + (size_t)l15 * 128 + c0);
            s8v b1 = *(const s8v*)(Vs[bf] + (size_t)(16 + l15) * 128 + c0);
            o00 = __builtin_amdgcn_mfma_f32_16x16x32_bf16(ap0, b0, o00, 0, 0, 0);
            o01 = __builtin_amdgcn_mfma_f32_16x16x32_bf16(ap0, b1, o01, 0, 0, 0);
            o10 = __builtin_amdgcn_mfma_f32_16x16x32_bf16(ap1, b0, o10, 0, 0, 0);
            o11 = __builtin_amdgcn_mfma_f32_16x16x32_bf16(ap1, b1, o11, 0, 0, 0);
            od0 = __builtin_amdgcn_mfma_f32_16x16x32_bf16(ap0, vone, od0, 0, 0, 0);
            od1 = __builtin_amdgcn_mfma_f32_16x16x32_bf16(ap1, vone, od1, 0, 0, 0);
        }
    }
#undef STAGE

#pragma unroll
    for (int r = 0; r < 4; ++r) {
        int row0 = q0 + quad * 4 + r;
        int row1 = row0 + 16;
        float i0v = 1.f / od0[r];
        float i1v = 1.f / od1[r];
        outb[(size_t)(b * 1024 + row0) * 256 + h * 32 + l15]      = f2bf(o00[r] * i0v);
        outb[(size_t)(b * 1024 + row0) * 256 + h * 32 + 16 + l15] = f2bf(o01[r] * i0v);
        outb[(size_t)(b * 1024 + row1) * 256 + h * 32 + l15]      = f2bf(o10[r] * i1v);
        outb[(size_t)(b * 1024 + row1) * 256 + h * 32 + 16 + l15] = f2bf(o11[r] * i1v);
    }
}

// ---------------------------------------------------------------------------
extern "C" void kernel_launch(void* const* d_in, const int* in_sizes, int n_in,
                              void* d_out, int out_size, void* d_ws, size_t ws_size,
                              hipStream_t stream)
{
    const float* x        = (const float*)d_in[0];
    const int*   ei       = (const int*)d_in[1];
    const float* gat_W0   = (const float*)d_in[3];
    const float* gat_W12  = (const float*)d_in[4];
    const float* att_src  = (const float*)d_in[5];
    const float* att_dst  = (const float*)d_in[6];
    const float* gat_bias = (const float*)d_in[7];
    const float* qkv_w    = (const float*)d_in[8];
    const float* qkv_b    = (const float*)d_in[9];
    const float* out_w    = (const float*)d_in[10];
    const float* out_b    = (const float*)d_in[11];
    const float* ln1_w    = (const float*)d_in[12];
    const float* ln1_b    = (const float*)d_in[13];
    const float* ln2_w    = (const float*)d_in[14];
    const float* ln2_b    = (const float*)d_in[15];
    const float* ff1_w    = (const float*)d_in[16];
    const float* ff1_b    = (const float*)d_in[17];
    const float* ff2_w    = (const float*)d_in[18];
    const float* ff2_b    = (const float*)d_in[19];
    const float* pred_w   = (const float*)d_in[20];
    const float* pred_b   = (const float*)d_in[21];
    float* outp = (float*)d_out;

    float* ws   = (float*)d_ws;
    float* hA   = ws;                                    // [8192,256] f32
    float* hB   = ws + 2097152;                          // [8192,256] f32
    ushort* ffb  = (ushort*)(ws + 4194304);              // [8192,2048] bf16
    ushort* Qb   = (ushort*)(ws + 12582912);             // [64][1024][32]
    ushort* Kb   = (ushort*)(ws + 13631488);
    ushort* Vt   = (ushort*)(ws + 14680064);             // [64][32][1024]
    ushort* attnb= (ushort*)(ws + 15728640);             // [8192,256] bf16
    ushort* lnb  = (ushort*)(ws + 16777216);             // [8192,256] bf16
    ushort* hBb  = (ushort*)(ws + 17825792);             // [8192,256] bf16
    ushort* xb   = (ushort*)(ws + 18874368);             // [8192,64] bf16
    ushort* wbase= (ushort*)(ws + 19136512);
    ushort* W0b    = wbase;
    ushort* W12b   = wbase + 16384;
    ushort* qkv_wb = wbase + 147456;
    ushort* out_wb = wbase + 540672;
    ushort* ff1_wb = wbase + 671744;
    ushort* ff2_wb = wbase + 1720320;
    float* a_s  = ws + 20520960;
    float* a_d  = ws + 20586496;
    int*   deg  = (int*)(ws + 20652032);                 // 8192 ints
    ushort* hAb    = (ushort*)(ws + 21000192);           // [8192,256] bf16
    int*   col  = (int*)(ws + 30437376);                 // [8192*128] padded CSR

    // ---- merged casts + deg zero ----
    castall_kernel<<<3216, 256, 0, stream>>>(
        gat_W0, gat_W12, qkv_w, out_w, ff1_w, ff2_w, x,
        W0b, W12b, qkv_wb, out_wb, ff1_wb, ff2_wb, xb, deg);

    // ---- GAT L0 GEMM + padded-CSR scatter (one dispatch) ----
    gemm0_scatter_kernel<<<1568, 256, 0, stream>>>(
        xb, W0b, hAb, att_src, att_dst, a_s, a_d, ei, deg, col);
    gat_agg_kernel<false><<<2048, 256, 0, stream>>>(
        hAb, a_s, a_d, deg, col, gat_bias, nullptr, hBb);

    // ---- GAT layers 1,2 ----
    for (int l = 0; l < 2; ++l) {
        mgemm64_kernel<true><<<dim3(128, 4), 256, 0, stream>>>(
            hBb, W12b + (size_t)l * DD * DD, hAb,
            att_src + (l + 1) * 256, att_dst + (l + 1) * 256, a_s, a_d, NN, DD, DD);
        if (l == 0)
            gat_agg_kernel<false><<<2048, 256, 0, stream>>>(
                hAb, a_s, a_d, deg, col, gat_bias + 256, nullptr, hBb);
        else
            gat_agg_kernel<true><<<2048, 256, 0, stream>>>(
                hAb, a_s, a_d, deg, col, gat_bias + 512, hB, hBb);
    }

    // ---- Transformer layers (x: fp32 in hB, bf16 in hBb at loop top) ----
    for (int l = 0; l < 2; ++l) {
        mgemm_qkv_kernel<<<dim3(128, 12), 256, 0, stream>>>(
            hBb, qkv_wb + (size_t)l * 768 * DD, qkv_b + l * 768, Qb, Kb, Vt, NN, DD);
        attn_flash_kernel<<<dim3(8, 64), 256, 0, stream>>>(Qb, Kb, Vt, attnb);
        // fused out-proj + bias + residual(hB) + LN1 -> hA (fp32) + lnb (bf16)
        mgemm_ln_kernel<false><<<256, 512, 0, stream>>>(
            attnb, out_wb + (size_t)l * DD * DD, out_b + l * DD, hB,
            ln1_w + l * DD, ln1_b + l * DD, hA, lnb,
            nullptr, nullptr, nullptr, NN, DD);
        mgemm_ff1_kernel<<<dim3(64, 16), 256, 0, stream>>>(
            lnb, ff1_wb + (size_t)l * DFFN * DD, ff1_b + l * DFFN, ffb, NN, DFFN, DD);
        if (l == 0) {
            mgemm_ln_kernel<false><<<256, 512, 0, stream>>>(
                ffb, ff2_wb, ff2_b, hA,
                ln2_w, ln2_b, hB, hBb,
                nullptr, nullptr, nullptr, NN, DFFN);
        } else {
            mgemm_ln_kernel<true><<<256, 512, 0, stream>>>(
                ffb, ff2_wb + (size_t)DD * DFFN, ff2_b + DD, hA,
                ln2_w + DD, ln2_b + DD, nullptr, nullptr,
                pred_w, pred_b, outp, NN, DFFN);
        }
    }
}